// Round 2
// baseline (2434.906 us; speedup 1.0000x reference)
//
#include <hip/hip_runtime.h>
#include <math.h>

// Problem constants
#define BB 32
#define TT 512
#define INF_ 128
#define HH 256
#define H3 768
#define NHEADS 4
#define HDIM 64

typedef _Float16 half_t;
typedef half_t half2_t __attribute__((ext_vector_type(2)));
typedef half_t half4_t __attribute__((ext_vector_type(4)));
typedef half_t f16x8 __attribute__((ext_vector_type(8)));
typedef float f32x4 __attribute__((ext_vector_type(4)));

// ---------------- wave helpers (wave = 64 on CDNA) ----------------
__device__ __forceinline__ float wsum(float v) {
#pragma unroll
  for (int o = 32; o > 0; o >>= 1) v += __shfl_xor(v, o, 64);
  return v;
}
__device__ __forceinline__ float wmax(float v) {
#pragma unroll
  for (int o = 32; o > 0; o >>= 1) v = fmaxf(v, __shfl_xor(v, o, 64));
  return v;
}

// ---------------- fp32 -> f16 cast (n % 1024 == 0) ----------------
__global__ void castk(const float* __restrict__ s, half_t* __restrict__ d, int n) {
  int i = (blockIdx.x * 256 + threadIdx.x) * 4;
  if (i < n) {
    float4 v = *(const float4*)(s + i);
    half4_t o = {(half_t)v.x, (half_t)v.y, (half_t)v.z, (half_t)v.w};
    *(half4_t*)(d + i) = o;
  }
}

// ---------------- MFMA f16 GEMM: C[M,N] = A[M,K] * B[N,K]^T + bias -------
__global__ __launch_bounds__(256) void gemm_f16(
    const half_t* __restrict__ A, const half_t* __restrict__ B,
    const float* __restrict__ bias, float* __restrict__ C,
    int M, int N, int K) {
  __shared__ __align__(16) half_t As[128][40];
  __shared__ __align__(16) half_t Bs[64][40];
  const int tid = threadIdx.x;
  const int wave = tid >> 6, lane = tid & 63;
  const int m0 = blockIdx.y * 128, n0 = blockIdx.x * 64;
  const int mrow = lane & 15, quad = lane >> 4;
  f32x4 acc00 = {0.f, 0.f, 0.f, 0.f}, acc01 = acc00, acc02 = acc00, acc03 = acc00;
  f32x4 acc10 = acc00, acc11 = acc00, acc12 = acc00, acc13 = acc00;
  for (int k0 = 0; k0 < K; k0 += 32) {
    __syncthreads();  // previous iter's fragments consumed
#pragma unroll
    for (int u = 0; u < 2; ++u) {  // stage A: 128 rows x 32 halfs
      int idx = tid + u * 256;
      int row = idx >> 2, seg = idx & 3;
      *(f16x8*)&As[row][seg * 8] =
          *(const f16x8*)&A[(size_t)(m0 + row) * K + k0 + seg * 8];
    }
    {  // stage B: 64 rows x 32 halfs
      int row = tid >> 2, seg = tid & 3;
      *(f16x8*)&Bs[row][seg * 8] =
          *(const f16x8*)&B[(size_t)(n0 + row) * K + k0 + seg * 8];
    }
    __syncthreads();
    f16x8 af0 = *(const f16x8*)&As[wave * 32 + mrow][quad * 8];
    f16x8 af1 = *(const f16x8*)&As[wave * 32 + 16 + mrow][quad * 8];
    f16x8 bf0 = *(const f16x8*)&Bs[mrow][quad * 8];
    f16x8 bf1 = *(const f16x8*)&Bs[16 + mrow][quad * 8];
    f16x8 bf2 = *(const f16x8*)&Bs[32 + mrow][quad * 8];
    f16x8 bf3 = *(const f16x8*)&Bs[48 + mrow][quad * 8];
    acc00 = __builtin_amdgcn_mfma_f32_16x16x32_f16(af0, bf0, acc00, 0, 0, 0);
    acc01 = __builtin_amdgcn_mfma_f32_16x16x32_f16(af0, bf1, acc01, 0, 0, 0);
    acc02 = __builtin_amdgcn_mfma_f32_16x16x32_f16(af0, bf2, acc02, 0, 0, 0);
    acc03 = __builtin_amdgcn_mfma_f32_16x16x32_f16(af0, bf3, acc03, 0, 0, 0);
    acc10 = __builtin_amdgcn_mfma_f32_16x16x32_f16(af1, bf0, acc10, 0, 0, 0);
    acc11 = __builtin_amdgcn_mfma_f32_16x16x32_f16(af1, bf1, acc11, 0, 0, 0);
    acc12 = __builtin_amdgcn_mfma_f32_16x16x32_f16(af1, bf2, acc12, 0, 0, 0);
    acc13 = __builtin_amdgcn_mfma_f32_16x16x32_f16(af1, bf3, acc13, 0, 0, 0);
  }
  float bv0 = bias ? bias[n0 + mrow] : 0.f;
  float bv1 = bias ? bias[n0 + 16 + mrow] : 0.f;
  float bv2 = bias ? bias[n0 + 32 + mrow] : 0.f;
  float bv3 = bias ? bias[n0 + 48 + mrow] : 0.f;
  const int rb = m0 + wave * 32 + quad * 4;
#pragma unroll
  for (int r = 0; r < 4; ++r) {
    float* c0 = C + (size_t)(rb + r) * N + n0;
    c0[mrow] = acc00[r] + bv0;
    c0[16 + mrow] = acc01[r] + bv1;
    c0[32 + mrow] = acc02[r] + bv2;
    c0[48 + mrow] = acc03[r] + bv3;
    float* c1 = C + (size_t)(rb + 16 + r) * N + n0;
    c1[mrow] = acc10[r] + bv0;
    c1[16 + mrow] = acc11[r] + bv1;
    c1[32 + mrow] = acc12[r] + bv2;
    c1[48 + mrow] = acc13[r] + bv3;
  }
}

// ---------------- GRU recurrence: per-wave gate-complete MFMA GEMV --------
// R1 post-mortem: MFMA GEMV with a cross-wave g-exchange (2 barriers, combine
// phase on 4/12 waves) serialized to 4040 cyc/step. Fix: wave w owns ALL
// THREE gate rows for units [16w,16w+16) -- rows u, 256+u, 512+u. With the
// broadcast-A trick (all 16 D rows identical), EVERY lane's acc[0] holds
// g[16w + (lane&15)], so (ar,az,an) land in-register in the same lane: gate
// math is per-lane (x4 quad-redundant, no divergence), h stays in regs, no
// g-exchange, ONE barrier/step. x-projection for step t+1 prefetched at step
// t so its HBM/L3 latency hides under MFMA+gate+barrier.
__device__ __forceinline__ f16x8 ldw8(const float* p) {
  float4 a = *(const float4*)p;
  float4 b = *(const float4*)(p + 4);
  return f16x8{(half_t)a.x, (half_t)a.y, (half_t)a.z, (half_t)a.w,
               (half_t)b.x, (half_t)b.y, (half_t)b.z, (half_t)b.w};
}

#define GDECL(g) f16x8 g##0, g##1, g##2, g##3, g##4, g##5, g##6, g##7;
#define GLOAD(g, base)                                                     \
  g##0 = ldw8((base) + 0 * 32);                                            \
  g##1 = ldw8((base) + 1 * 32);                                            \
  g##2 = ldw8((base) + 2 * 32);                                            \
  g##3 = ldw8((base) + 3 * 32);                                            \
  g##4 = ldw8((base) + 4 * 32);                                            \
  g##5 = ldw8((base) + 5 * 32);                                            \
  g##6 = ldw8((base) + 6 * 32);                                            \
  g##7 = ldw8((base) + 7 * 32);
// one K-tile: 3 MFMAs (r,z,n) -> dep chains spaced by 3 on the matrix pipe
#define MQ(k)                                                                  \
  accR = __builtin_amdgcn_mfma_f32_16x16x32_f16(a##k, wr##k, accR, 0, 0, 0);   \
  accZ = __builtin_amdgcn_mfma_f32_16x16x32_f16(a##k, wz##k, accZ, 0, 0, 0);   \
  accN = __builtin_amdgcn_mfma_f32_16x16x32_f16(a##k, wn##k, accN, 0, 0, 0);

__global__ __launch_bounds__(1024) void gru_layer(
    const float* __restrict__ xp, const float* __restrict__ Whh,
    const float* __restrict__ bhh, float* __restrict__ out,
    half_t* __restrict__ out16) {
  __shared__ __align__(16) half_t hs[2][256];   // packed f16 hidden state
  const int tid = threadIdx.x;
  const int w = tid >> 6, lane = tid & 63;
  const int col = lane & 15, quad = lane >> 4;
  const int u = 16 * w + col;  // this lane's hidden unit (x4 quad-redundant)
  const int b = blockIdx.x;
  const bool wf32 = (out != nullptr);  // uniform: layer 0 skips fp32 h-store

  // B-fragments: rows u (r), 256+u (z), 512+u (n); k = kt*32 + quad*8.
  GDECL(wr) GDECL(wz) GDECL(wn)
  {
    const float* baseR = Whh + (size_t)u * HH + quad * 8;
    const float* baseZ = Whh + (size_t)(HH + u) * HH + quad * 8;
    const float* baseN = Whh + (size_t)(2 * HH + u) * HH + quad * 8;
    GLOAD(wr, baseR)
    GLOAD(wz, baseZ)
    GLOAD(wn, baseN)
  }
  const float br = bhh[u], bz = bhh[HH + u], bn = bhh[2 * HH + u];
  float hprev = 0.f;
  if (tid < 256) hs[0][tid] = (half_t)0.f;
  __syncthreads();

  const float* xrow = xp + (size_t)b * TT * H3;
  half_t* orow16 = out16 + (size_t)b * TT * HH;
  float* orow = wf32 ? (out + (size_t)b * TT * HH) : nullptr;

  // x-projection for step 0
  float xr = xrow[u], xz = xrow[HH + u], xn = xrow[2 * HH + u];

  for (int t = 0; t < TT; ++t) {
    // prefetch next step's x-projection (hides HBM/L3 latency under this step)
    float nxr = 0.f, nxz = 0.f, nxn = 0.f;
    if (t + 1 < TT) {
      const float* xnx = xrow + H3;
      nxr = xnx[u]; nxz = xnx[HH + u]; nxn = xnx[2 * HH + u];
    }
    // A-fragments: 8 broadcast b128 reads of h (addr depends on quad only)
    const half_t* hb = &hs[t & 1][quad * 8];
    f16x8 a0 = *(const f16x8*)(hb + 0 * 32);
    f16x8 a1 = *(const f16x8*)(hb + 1 * 32);
    f16x8 a2 = *(const f16x8*)(hb + 2 * 32);
    f16x8 a3 = *(const f16x8*)(hb + 3 * 32);
    f16x8 a4 = *(const f16x8*)(hb + 4 * 32);
    f16x8 a5 = *(const f16x8*)(hb + 5 * 32);
    f16x8 a6 = *(const f16x8*)(hb + 6 * 32);
    f16x8 a7 = *(const f16x8*)(hb + 7 * 32);
    f32x4 accR = {0.f, 0.f, 0.f, 0.f}, accZ = accR, accN = accR;
    MQ(0) MQ(1) MQ(2) MQ(3) MQ(4) MQ(5) MQ(6) MQ(7)
    // every lane: acc[0] = g for unit u (all D rows identical)
    float ar = accR[0], az = accZ[0], an = accN[0];
    float rg = 1.f / (1.f + __expf(-(xr + ar + br)));
    float zg = 1.f / (1.f + __expf(-(xz + az + bz)));
    float ng = 2.f / (1.f + __expf(-2.f * (xn + rg * (an + bn)))) - 1.f;  // tanh, inf-safe
    float hnew = (1.f - zg) * ng + zg * hprev;
    hprev = hnew;
    if (quad == 0) {
      hs[(t + 1) & 1][u] = (half_t)hnew;
      orow16[u] = (half_t)hnew;
      if (wf32) orow[u] = hnew;
    }
    __syncthreads();  // h(t+1) visible before next step's A-frag reads
    xr = nxr; xz = nxz; xn = nxn;
    xrow += H3;
    orow16 += HH;
    if (wf32) orow += HH;
  }
}

// ---------------- gat_W transpose -> f16: [4,256,64] -> [256 cols][256 k] --
__global__ void gat_wt(const float* __restrict__ W, half_t* __restrict__ Wt) {
  int idx = blockIdx.x * 256 + threadIdx.x;  // [0, 65536)
  int col = idx >> 8, k = idx & 255;
  Wt[idx] = (half_t)W[((size_t)((col >> 6) * HH + k)) * HDIM + (col & 63)];
}

// ---------------- GAT f_src/f_dst ----------------
__global__ void gat_fsd(const float* __restrict__ hgat, const float* __restrict__ a,
                        float* __restrict__ fsrc, float* __restrict__ fdst) {
  int b = blockIdx.x, hd = blockIdx.y, t = threadIdx.x;  // block 512
  const float* hp = hgat + ((size_t)(b * TT + t)) * HH + hd * HDIM;
  const float* ap = a + hd * 2 * HDIM;
  float fs = 0.f, fd = 0.f;
#pragma unroll 4
  for (int d = 0; d < HDIM; ++d) {
    float hv = hp[d];
    fs += hv * ap[d];
    fd += hv * ap[HDIM + d];
  }
  fsrc[(b * NHEADS + hd) * TT + t] = fs;
  fdst[(b * NHEADS + hd) * TT + t] = fd;
}

// ---------------- GAT flash attention ----------------
__global__ __launch_bounds__(256) void gat_attn(
    const float* __restrict__ hgat, const float* __restrict__ fsrc,
    const float* __restrict__ fdst, float* __restrict__ out) {
  __shared__ __align__(16) float Ht[128][64];
  __shared__ __align__(16) float fd[128];
  __shared__ __align__(16) float pq[4][128][8];
  const int tid = threadIdx.x, wave = tid >> 6, lane = tid & 63;
  const int hd = blockIdx.y, b = blockIdx.z;
  const int i0 = blockIdx.x * 32 + wave * 8;
  const float* fs = fsrc + (size_t)(b * NHEADS + hd) * TT;
  const float* fdp = fdst + (size_t)(b * NHEADS + hd) * TT;
  float m[8], l[8], acc[8], fi[8];
#pragma unroll
  for (int q = 0; q < 8; ++q) { m[q] = -1e30f; l[q] = 0.f; acc[q] = 0.f; fi[q] = fs[i0 + q]; }
  for (int jt = 0; jt < TT; jt += 128) {
#pragma unroll
    for (int u = 0; u < 8; ++u) {
      int idx = tid + u * 256;
      int jj = idx >> 4, dq = (idx & 15) * 4;
      *(float4*)&Ht[jj][dq] =
          *(const float4*)&hgat[((size_t)(b * TT + jt + jj)) * HH + hd * HDIM + dq];
    }
    if (tid < 128) fd[tid] = fdp[jt + tid];
    __syncthreads();
#pragma unroll
    for (int q = 0; q < 8; ++q) {
      float e0 = fi[q] + fd[lane];      e0 = (e0 > 0.f) ? e0 : 0.2f * e0;
      float e1 = fi[q] + fd[lane + 64]; e1 = (e1 > 0.f) ? e1 : 0.2f * e1;
      float mn = fmaxf(m[q], wmax(fmaxf(e0, e1)));
      float corr = __expf(m[q] - mn);
      float p0 = __expf(e0 - mn), p1 = __expf(e1 - mn);
      l[q] = l[q] * corr + wsum(p0 + p1);
      m[q] = mn;
      acc[q] *= corr;
      pq[wave][lane][q] = p0;
      pq[wave][lane + 64][q] = p1;
    }
#pragma unroll 4
    for (int jj = 0; jj < 128; ++jj) {
      float4 pa = *(const float4*)&pq[wave][jj][0];
      float4 pb = *(const float4*)&pq[wave][jj][4];
      float hv = Ht[jj][lane];
      acc[0] += pa.x * hv; acc[1] += pa.y * hv; acc[2] += pa.z * hv; acc[3] += pa.w * hv;
      acc[4] += pb.x * hv; acc[5] += pb.y * hv; acc[6] += pb.z * hv; acc[7] += pb.w * hv;
    }
    __syncthreads();
  }
#pragma unroll
  for (int q = 0; q < 8; ++q)
    out[((size_t)(b * TT + i0 + q)) * HH + hd * HDIM + lane] = acc[q] / l[q];
}

// ---------------- residual + LayerNorm (f16 output for MFMA GEMM) ---------
__global__ __launch_bounds__(256) void ln_res(
    const float* __restrict__ g, const float* __restrict__ gat,
    const float* __restrict__ gamma, const float* __restrict__ beta,
    half_t* __restrict__ y16) {
  int wave = threadIdx.x >> 6, lane = threadIdx.x & 63;
  size_t n = (size_t)blockIdx.x * 4 + wave;
  float4 v = ((const float4*)(g + n * HH))[lane];
  float4 w = ((const float4*)(gat + n * HH))[lane];
  v.x += w.x; v.y += w.y; v.z += w.z; v.w += w.w;
  float mu = wsum(v.x + v.y + v.z + v.w) * (1.f / 256.f);
  float dx = v.x - mu, dy = v.y - mu, dz = v.z - mu, dw = v.w - mu;
  float var = wsum(dx * dx + dy * dy + dz * dz + dw * dw) * (1.f / 256.f);
  float rstd = rsqrtf(var + 1e-5f);
  float4 gm = ((const float4*)gamma)[lane];
  float4 bt = ((const float4*)beta)[lane];
  half4_t o = {(half_t)(dx * rstd * gm.x + bt.x), (half_t)(dy * rstd * gm.y + bt.y),
               (half_t)(dz * rstd * gm.z + bt.z), (half_t)(dw * rstd * gm.w + bt.w)};
  ((half4_t*)(y16 + n * HH))[lane] = o;
}

// ---------------- MHA flash attention (f16 ctx output) --------------------
__global__ __launch_bounds__(256) void mha_attn(const float* __restrict__ qkv,
                                                half_t* __restrict__ ctx16) {
  __shared__ __align__(16) float KV[8320];        // K^T [64][130] | V [128][64]
  __shared__ __align__(16) float qq[4][64][8];
  __shared__ __align__(16) float pq[4][128][8];
  const int tid = threadIdx.x, wave = tid >> 6, lane = tid & 63;
  const int hd = blockIdx.y, b = blockIdx.z;
  const int i0 = blockIdx.x * 32 + wave * 8;
#pragma unroll
  for (int q = 0; q < 8; ++q)
    qq[wave][lane][q] = qkv[((size_t)(b * TT + i0 + q)) * H3 + hd * HDIM + lane];
  float m[8], l[8], acc[8];
#pragma unroll
  for (int q = 0; q < 8; ++q) { m[q] = -1e30f; l[q] = 0.f; acc[q] = 0.f; }
  for (int jt = 0; jt < TT; jt += 128) {
    // stage K^T: KV[dd*130 + j]
#pragma unroll
    for (int u = 0; u < 8; ++u) {
      int idx = tid + u * 256;
      int jj = idx >> 4, dq = (idx & 15) * 4;
      float4 kv = *(const float4*)&qkv[((size_t)(b * TT + jt + jj)) * H3 + HH + hd * HDIM + dq];
      KV[(dq + 0) * 130 + jj] = kv.x;
      KV[(dq + 1) * 130 + jj] = kv.y;
      KV[(dq + 2) * 130 + jj] = kv.z;
      KV[(dq + 3) * 130 + jj] = kv.w;
    }
    __syncthreads();
    float e0[8] = {}, e1[8] = {};
#pragma unroll 8
    for (int dd = 0; dd < 64; ++dd) {
      float4 qa = *(const float4*)&qq[wave][dd][0];
      float4 qb = *(const float4*)&qq[wave][dd][4];
      float k0 = KV[dd * 130 + lane], k1 = KV[dd * 130 + 64 + lane];
      e0[0] += qa.x * k0; e0[1] += qa.y * k0; e0[2] += qa.z * k0; e0[3] += qa.w * k0;
      e0[4] += qb.x * k0; e0[5] += qb.y * k0; e0[6] += qb.z * k0; e0[7] += qb.w * k0;
      e1[0] += qa.x * k1; e1[1] += qa.y * k1; e1[2] += qa.z * k1; e1[3] += qa.w * k1;
      e1[4] += qb.x * k1; e1[5] += qb.y * k1; e1[6] += qb.z * k1; e1[7] += qb.w * k1;
    }
    __syncthreads();  // done reading K^T
    // stage V over the same buffer: KV[j*64 + dd]
#pragma unroll
    for (int u = 0; u < 8; ++u) {
      int idx = tid + u * 256;
      int jj = idx >> 4, dq = (idx & 15) * 4;
      *(float4*)&KV[jj * 64 + dq] =
          *(const float4*)&qkv[((size_t)(b * TT + jt + jj)) * H3 + 2 * HH + hd * HDIM + dq];
    }
#pragma unroll
    for (int q = 0; q < 8; ++q) {
      float s0 = e0[q] * 0.125f, s1 = e1[q] * 0.125f;
      float mn = fmaxf(m[q], wmax(fmaxf(s0, s1)));
      float corr = __expf(m[q] - mn);
      float p0 = __expf(s0 - mn), p1 = __expf(s1 - mn);
      l[q] = l[q] * corr + wsum(p0 + p1);
      m[q] = mn;
      acc[q] *= corr;
      pq[wave][lane][q] = p0;
      pq[wave][lane + 64][q] = p1;
    }
    __syncthreads();  // V staged, pq written
#pragma unroll 4
    for (int jj = 0; jj < 128; ++jj) {
      float4 pa = *(const float4*)&pq[wave][jj][0];
      float4 pb = *(const float4*)&pq[wave][jj][4];
      float hv = KV[jj * 64 + lane];
      acc[0] += pa.x * hv; acc[1] += pa.y * hv; acc[2] += pa.z * hv; acc[3] += pa.w * hv;
      acc[4] += pb.x * hv; acc[5] += pb.y * hv; acc[6] += pb.z * hv; acc[7] += pb.w * hv;
    }
    __syncthreads();  // before next K^T overwrite
  }
#pragma unroll
  for (int q = 0; q < 8; ++q)
    ctx16[((size_t)(b * TT + i0 + q)) * HH + hd * HDIM + lane] = (half_t)(acc[q] / l[q]);
}

// ---------------- mean pool over T ----------------
__global__ void mean_pool(const float* __restrict__ x, float* __restrict__ out) {
  int b = blockIdx.x, j = threadIdx.x;
  const float* p = x + (size_t)b * TT * HH + j;
  float s = 0.f;
  for (int t = 0; t < TT; ++t) s += p[(size_t)t * HH];
  out[b * HH + j] = s * (1.f / 512.f);
}

// ---------------- FC layers ----------------
__global__ void fc1_k(const float* __restrict__ pooled, const float* __restrict__ w,
                      const float* __restrict__ bias, float* __restrict__ hid) {
  int b = blockIdx.x, o = threadIdx.x;  // 128 threads
  const float* pp = pooled + b * HH;
  const float* wp = w + o * HH;
  float s = 0.f;
#pragma unroll 4
  for (int k = 0; k < HH; ++k) s += pp[k] * wp[k];
  hid[b * 128 + o] = fmaxf(s + bias[o], 0.f);
}

__global__ void fc2_k(const float* __restrict__ hid, const float* __restrict__ w,
                      const float* __restrict__ bias, float* __restrict__ out) {
  int t = threadIdx.x;  // 256 = 32 m x 8 c
  int mm = t >> 3, c = t & 7;
  const float* hp = hid + mm * 128;
  const float* wp = w + c * 128;
  float s = 0.f;
#pragma unroll 4
  for (int k = 0; k < 128; ++k) s += hp[k] * wp[k];
  out[mm * 8 + c] = s + bias[c];
}

extern "C" void kernel_launch(void* const* d_in, const int* in_sizes, int n_in,
                              void* d_out, int out_size, void* d_ws, size_t ws_size,
                              hipStream_t stream) {
  (void)in_sizes; (void)n_in; (void)out_size; (void)ws_size;
  const float* x    = (const float*)d_in[0];
  const float* Wih0 = (const float*)d_in[1];
  const float* Whh0 = (const float*)d_in[2];
  const float* bih0 = (const float*)d_in[3];
  const float* bhh0 = (const float*)d_in[4];
  const float* Wih1 = (const float*)d_in[5];
  const float* Whh1 = (const float*)d_in[6];
  const float* bih1 = (const float*)d_in[7];
  const float* bhh1 = (const float*)d_in[8];
  const float* gatW = (const float*)d_in[9];
  const float* gatA = (const float*)d_in[10];
  const float* lng  = (const float*)d_in[11];
  const float* lnb  = (const float*)d_in[12];
  const float* inw  = (const float*)d_in[13];
  const float* inb  = (const float*)d_in[14];
  const float* outw = (const float*)d_in[15];
  const float* outb = (const float*)d_in[16];
  const float* f1w  = (const float*)d_in[17];
  const float* f1b  = (const float*)d_in[18];
  const float* f2w  = (const float*)d_in[19];
  const float* f2b  = (const float*)d_in[20];
  float* out = (float*)d_out;
  float* ws = (float*)d_ws;

  // fp32 regions:
  float* XPA   = ws;                  // 16384*768: xp0 -> xp1 -> qkv
  float* G0    = ws + 12582912;       // gat_out (gru0 fp32 h never stored)
  float* G1    = G0 + 4194304;        // gru1-out (fp32, for ln_res)
  float* Yb    = G1 + 4194304;        // [f16 G0_16 | f16 G1_16] -> attn_out fp32
  float* HGAT  = Yb + 4194304;        // gat feats fp32 -> [f16 CTX16 | f16 Y16]
  float* GATWTf= HGAT + 4194304;
  float* FSRC  = GATWTf + 65536;
  float* FDST  = FSRC + 65536;
  float* POOL  = FDST + 65536;
  float* HIDb  = POOL + 8192;
  float* W16b  = HIDb + 4096;         // f16 weight pool (~1.1 MB)

  // f16 aliases (lifetimes verified against launch order):
  half_t* X16     = (half_t*)G1;                   // dead before gru1 writes G1
  half_t* G0_16   = (half_t*)Yb;                   // dead before attn_out write
  half_t* G1_16   = (half_t*)(Yb + 2097152);
  half_t* CTX16   = (half_t*)HGAT;                 // written after gat phase done
  half_t* Y16     = (half_t*)(HGAT + 2097152);
  half_t* GATWT16 = (half_t*)GATWTf;
  half_t* W16ih0  = (half_t*)W16b;
  half_t* W16ih1  = (half_t*)(W16b + 49152);
  half_t* W16in   = (half_t*)(W16b + 49152 + 98304);
  half_t* W16out  = (half_t*)(W16b + 49152 + 98304 + 98304);

  // 0. casts (weights once; x once)
  castk<<<2048, 256, 0, stream>>>(x, X16, 2097152);
  castk<<<96, 256, 0, stream>>>(Wih0, W16ih0, 98304);
  castk<<<192, 256, 0, stream>>>(Wih1, W16ih1, 196608);
  castk<<<192, 256, 0, stream>>>(inw, W16in, 196608);
  castk<<<64, 256, 0, stream>>>(outw, W16out, 65536);
  gat_wt<<<256, 256, 0, stream>>>(gatW, GATWT16);
  // 1. xp0 = x @ W_ih0^T + b_ih0   (MFMA f16)
  gemm_f16<<<dim3(12, 128), 256, 0, stream>>>(X16, W16ih0, bih0, XPA, 16384, 768, 128);
  // 2. GRU layer 0 (fp32 h not needed -> nullptr)
  gru_layer<<<32, 1024, 0, stream>>>(XPA, Whh0, bhh0, nullptr, G0_16);
  // 3. xp1 = g0 @ W_ih1^T + b_ih1
  gemm_f16<<<dim3(12, 128), 256, 0, stream>>>(G0_16, W16ih1, bih1, XPA, 16384, 768, 256);
  // 4. GRU layer 1
  gru_layer<<<32, 1024, 0, stream>>>(XPA, Whh1, bhh1, G1, G1_16);
  // 5. GAT per-head features + attention
  gemm_f16<<<dim3(4, 128), 256, 0, stream>>>(G1_16, GATWT16, nullptr, HGAT, 16384, 256, 256);
  gat_fsd<<<dim3(32, 4), 512, 0, stream>>>(HGAT, gatA, FSRC, FDST);
  gat_attn<<<dim3(16, 4, 32), 256, 0, stream>>>(HGAT, FSRC, FDST, G0);
  // 6. y = LN(g + gat_out) -> f16
  ln_res<<<4096, 256, 0, stream>>>(G1, G0, lng, lnb, Y16);
  // 7. MHA
  gemm_f16<<<dim3(12, 128), 256, 0, stream>>>(Y16, W16in, inb, XPA, 16384, 768, 256);
  mha_attn<<<dim3(16, 4, 32), 256, 0, stream>>>(XPA, CTX16);
  gemm_f16<<<dim3(4, 128), 256, 0, stream>>>(CTX16, W16out, outb, Yb, 16384, 256, 256);
  // 8. pool + FC head
  mean_pool<<<32, 256, 0, stream>>>(Yb, POOL);
  fc1_k<<<32, 128, 0, stream>>>(POOL, f1w, f1b, HIDb);
  fc2_k<<<1, 256, 0, stream>>>(HIDb, f2w, f2b, out);
}

// Round 3
// 2059.940 us; speedup vs baseline: 1.1820x; 1.1820x over previous
//
#include <hip/hip_runtime.h>
#include <math.h>

// Problem constants
#define BB 32
#define TT 512
#define INF_ 128
#define HH 256
#define H3 768
#define NHEADS 4
#define HDIM 64

typedef _Float16 half_t;
typedef half_t half2_t __attribute__((ext_vector_type(2)));
typedef half_t half4_t __attribute__((ext_vector_type(4)));
typedef half_t f16x8 __attribute__((ext_vector_type(8)));
typedef float f32x4 __attribute__((ext_vector_type(4)));

// ---------------- wave helpers (wave = 64 on CDNA) ----------------
__device__ __forceinline__ float wsum(float v) {
#pragma unroll
  for (int o = 32; o > 0; o >>= 1) v += __shfl_xor(v, o, 64);
  return v;
}
__device__ __forceinline__ float wmax(float v) {
#pragma unroll
  for (int o = 32; o > 0; o >>= 1) v = fmaxf(v, __shfl_xor(v, o, 64));
  return v;
}

// ---------------- fp32 -> f16 cast (n % 1024 == 0) ----------------
__global__ void castk(const float* __restrict__ s, half_t* __restrict__ d, int n) {
  int i = (blockIdx.x * 256 + threadIdx.x) * 4;
  if (i < n) {
    float4 v = *(const float4*)(s + i);
    half4_t o = {(half_t)v.x, (half_t)v.y, (half_t)v.z, (half_t)v.w};
    *(half4_t*)(d + i) = o;
  }
}

// ---------------- MFMA f16 GEMM: C[M,N] = A[M,K] * B[N,K]^T + bias -------
__global__ __launch_bounds__(256) void gemm_f16(
    const half_t* __restrict__ A, const half_t* __restrict__ B,
    const float* __restrict__ bias, float* __restrict__ C,
    int M, int N, int K) {
  __shared__ __align__(16) half_t As[128][40];
  __shared__ __align__(16) half_t Bs[64][40];
  const int tid = threadIdx.x;
  const int wave = tid >> 6, lane = tid & 63;
  const int m0 = blockIdx.y * 128, n0 = blockIdx.x * 64;
  const int mrow = lane & 15, quad = lane >> 4;
  f32x4 acc00 = {0.f, 0.f, 0.f, 0.f}, acc01 = acc00, acc02 = acc00, acc03 = acc00;
  f32x4 acc10 = acc00, acc11 = acc00, acc12 = acc00, acc13 = acc00;
  for (int k0 = 0; k0 < K; k0 += 32) {
    __syncthreads();  // previous iter's fragments consumed
#pragma unroll
    for (int u = 0; u < 2; ++u) {  // stage A: 128 rows x 32 halfs
      int idx = tid + u * 256;
      int row = idx >> 2, seg = idx & 3;
      *(f16x8*)&As[row][seg * 8] =
          *(const f16x8*)&A[(size_t)(m0 + row) * K + k0 + seg * 8];
    }
    {  // stage B: 64 rows x 32 halfs
      int row = tid >> 2, seg = tid & 3;
      *(f16x8*)&Bs[row][seg * 8] =
          *(const f16x8*)&B[(size_t)(n0 + row) * K + k0 + seg * 8];
    }
    __syncthreads();
    f16x8 af0 = *(const f16x8*)&As[wave * 32 + mrow][quad * 8];
    f16x8 af1 = *(const f16x8*)&As[wave * 32 + 16 + mrow][quad * 8];
    f16x8 bf0 = *(const f16x8*)&Bs[mrow][quad * 8];
    f16x8 bf1 = *(const f16x8*)&Bs[16 + mrow][quad * 8];
    f16x8 bf2 = *(const f16x8*)&Bs[32 + mrow][quad * 8];
    f16x8 bf3 = *(const f16x8*)&Bs[48 + mrow][quad * 8];
    acc00 = __builtin_amdgcn_mfma_f32_16x16x32_f16(af0, bf0, acc00, 0, 0, 0);
    acc01 = __builtin_amdgcn_mfma_f32_16x16x32_f16(af0, bf1, acc01, 0, 0, 0);
    acc02 = __builtin_amdgcn_mfma_f32_16x16x32_f16(af0, bf2, acc02, 0, 0, 0);
    acc03 = __builtin_amdgcn_mfma_f32_16x16x32_f16(af0, bf3, acc03, 0, 0, 0);
    acc10 = __builtin_amdgcn_mfma_f32_16x16x32_f16(af1, bf0, acc10, 0, 0, 0);
    acc11 = __builtin_amdgcn_mfma_f32_16x16x32_f16(af1, bf1, acc11, 0, 0, 0);
    acc12 = __builtin_amdgcn_mfma_f32_16x16x32_f16(af1, bf2, acc12, 0, 0, 0);
    acc13 = __builtin_amdgcn_mfma_f32_16x16x32_f16(af1, bf3, acc13, 0, 0, 0);
  }
  float bv0 = bias ? bias[n0 + mrow] : 0.f;
  float bv1 = bias ? bias[n0 + 16 + mrow] : 0.f;
  float bv2 = bias ? bias[n0 + 32 + mrow] : 0.f;
  float bv3 = bias ? bias[n0 + 48 + mrow] : 0.f;
  const int rb = m0 + wave * 32 + quad * 4;
#pragma unroll
  for (int r = 0; r < 4; ++r) {
    float* c0 = C + (size_t)(rb + r) * N + n0;
    c0[mrow] = acc00[r] + bv0;
    c0[16 + mrow] = acc01[r] + bv1;
    c0[32 + mrow] = acc02[r] + bv2;
    c0[48 + mrow] = acc03[r] + bv3;
    float* c1 = C + (size_t)(rb + 16 + r) * N + n0;
    c1[mrow] = acc10[r] + bv0;
    c1[16 + mrow] = acc11[r] + bv1;
    c1[32 + mrow] = acc12[r] + bv2;
    c1[48 + mrow] = acc13[r] + bv3;
  }
}

// ---------------- GRU recurrence: MFMA GEMV, zero inner-loop vmem ---------
// R2 post-mortem: 1024-thr config forced total regs <=128/wave; the 96
// weight regs + working set spilled to scratch (L2-cached, so invisible in
// FETCH_SIZE) and reloaded EVERY step. Also every per-step barrier emits
// s_waitcnt vmcnt(0), draining the in-flight x-prefetch (HBM ~900cy) and
// h-stores -- a full HBM round-trip on each of 512 steps.
// Fix: 512 thr (8 waves, 2/SIMD -> 256-reg budget). Wave w owns units
// [32w,32w+32) x 3 gates = 48 resident weight frags (192 regs); the two
// 16-unit tiles are computed sequentially reusing 3 accs + pair-streamed
// broadcast a-frags (peak ~235 regs, no spill). Inner loop touches NO
// global memory: x-projection staged to LDS in 16-step chunks, h outputs
// buffered in LDS rings and flushed at super-step boundaries, so inner
// barriers have vmcnt==0 (free) and the one HBM latency per boundary is
// amortized 16x.
__device__ __forceinline__ f16x8 ldw8(const float* p) {
  float4 a = *(const float4*)p;
  float4 b = *(const float4*)(p + 4);
  return f16x8{(half_t)a.x, (half_t)a.y, (half_t)a.z, (half_t)a.w,
               (half_t)b.x, (half_t)b.y, (half_t)b.z, (half_t)b.w};
}

#define GDECL8(g) f16x8 g##0, g##1, g##2, g##3, g##4, g##5, g##6, g##7;
#define GLOAD8(g, base)            \
  {                                \
    const float* _p = (base);      \
    g##0 = ldw8(_p + 0 * 32);      \
    g##1 = ldw8(_p + 1 * 32);      \
    g##2 = ldw8(_p + 2 * 32);      \
    g##3 = ldw8(_p + 3 * 32);      \
    g##4 = ldw8(_p + 4 * 32);      \
    g##5 = ldw8(_p + 5 * 32);      \
    g##6 = ldw8(_p + 6 * 32);      \
    g##7 = ldw8(_p + 7 * 32);      \
  }
#define MQ3(p, R, Z, N)                                               \
  aR = __builtin_amdgcn_mfma_f32_16x16x32_f16(p, R, aR, 0, 0, 0);     \
  aZ = __builtin_amdgcn_mfma_f32_16x16x32_f16(p, Z, aZ, 0, 0, 0);     \
  aN = __builtin_amdgcn_mfma_f32_16x16x32_f16(p, N, aN, 0, 0, 0);
#define LDH(k) (*(const f16x8*)(hb + (k) * 32))
#define TILE8(rg, zg, ng)                                 \
  {                                                       \
    f16x8 p0 = LDH(0), p1 = LDH(1), p2 = LDH(2), p3 = LDH(3); \
    MQ3(p0, rg##0, zg##0, ng##0)                          \
    MQ3(p1, rg##1, zg##1, ng##1)                          \
    MQ3(p2, rg##2, zg##2, ng##2)                          \
    MQ3(p3, rg##3, zg##3, ng##3)                          \
    p0 = LDH(4); p1 = LDH(5); p2 = LDH(6); p3 = LDH(7);   \
    MQ3(p0, rg##4, zg##4, ng##4)                          \
    MQ3(p1, rg##5, zg##5, ng##5)                          \
    MQ3(p2, rg##6, zg##6, ng##6)                          \
    MQ3(p3, rg##7, zg##7, ng##7)                          \
  }
#define GATE(hp, BR, BZ, BN, U)                                               \
  {                                                                           \
    float ar = aR[0], az = aZ[0], an = aN[0];                                 \
    float xr = xs[xb + (U)], xz = xs[xb + 256 + (U)], xn = xs[xb + 512 + (U)];\
    float rg_ = 1.f / (1.f + __expf(-(xr + ar + BR)));                        \
    float zg_ = 1.f / (1.f + __expf(-(xz + az + BZ)));                        \
    float ng_ = 2.f / (1.f + __expf(-2.f * (xn + rg_ * (an + BN)))) - 1.f;    \
    float hnew = (1.f - zg_) * ng_ + zg_ * hp;                                \
    hp = hnew;                                                                \
    if (quad == 0) {                                                          \
      hs[(tt + 1) & 1][U] = (half_t)hnew;                                     \
      ring16[tt][U] = (half_t)hnew;                                           \
      if (wf32) ring32[tt][U] = hnew;                                         \
    }                                                                         \
  }

__global__ __launch_bounds__(512, 2) void gru_layer(
    const float* __restrict__ xp, const float* __restrict__ Whh,
    const float* __restrict__ bhh, float* __restrict__ out,
    half_t* __restrict__ out16) {
  __shared__ __align__(16) float xs[16 * H3];        // 48 KB x-proj chunk
  __shared__ __align__(16) half_t hs[2][256];        // 1 KB h ping-pong
  __shared__ __align__(16) half_t ring16[16][256];   // 8 KB f16 out ring
  __shared__ __align__(16) float ring32[16][256];    // 16 KB fp32 out ring
  const int tid = threadIdx.x;
  const int w = tid >> 6, lane = tid & 63;
  const int col = lane & 15, quad = lane >> 4;
  const int u0 = 32 * w + col, u1 = u0 + 16;  // this lane's 2 hidden units
  const int b = blockIdx.x;
  const bool wf32 = (out != nullptr);  // uniform: layer 0 skips fp32 h-store

  // Resident weight fragments: rows u (r), 256+u (z), 512+u (n) for both
  // unit tiles; lane k-offset = quad*8, frag kt at +kt*32.
  GDECL8(wr0_) GDECL8(wz0_) GDECL8(wn0_)
  GDECL8(wr1_) GDECL8(wz1_) GDECL8(wn1_)
  GLOAD8(wr0_, Whh + (size_t)u0 * HH + quad * 8)
  GLOAD8(wr1_, Whh + (size_t)u1 * HH + quad * 8)
  GLOAD8(wz0_, Whh + (size_t)(HH + u0) * HH + quad * 8)
  GLOAD8(wz1_, Whh + (size_t)(HH + u1) * HH + quad * 8)
  GLOAD8(wn0_, Whh + (size_t)(2 * HH + u0) * HH + quad * 8)
  GLOAD8(wn1_, Whh + (size_t)(2 * HH + u1) * HH + quad * 8)
  const float br0 = bhh[u0], bz0 = bhh[HH + u0], bn0 = bhh[2 * HH + u0];
  const float br1 = bhh[u1], bz1 = bhh[HH + u1], bn1 = bhh[2 * HH + u1];
  float hprev0 = 0.f, hprev1 = 0.f;

  const float* xbase = xp + (size_t)b * TT * H3;
  half_t* orow16 = out16 + (size_t)b * TT * HH;
  float* orow = wf32 ? (out + (size_t)b * TT * HH) : nullptr;

  // prologue: stage chunk 0, zero h
  {
    const float4* src = (const float4*)xbase;
    float4* xd = (float4*)xs;
#pragma unroll
    for (int k = 0; k < 6; ++k) xd[tid + k * 512] = src[tid + k * 512];
  }
  if (tid < 256) hs[0][tid] = (half_t)0.f;
  __syncthreads();

  for (int c = 0; c < 32; ++c) {  // 32 super-steps x 16 steps
#pragma unroll 2
    for (int tt = 0; tt < 16; ++tt) {
      const half_t* hb = &hs[tt & 1][quad * 8];
      const int xb = tt * H3;
      {
        f32x4 aR = {0.f, 0.f, 0.f, 0.f}, aZ = aR, aN = aR;
        TILE8(wr0_, wz0_, wn0_)
        GATE(hprev0, br0, bz0, bn0, u0)
      }
      {
        f32x4 aR = {0.f, 0.f, 0.f, 0.f}, aZ = aR, aN = aR;
        TILE8(wr1_, wz1_, wn1_)
        GATE(hprev1, br1, bz1, bn1, u1)
      }
      __syncthreads();  // h(t+1) visible; no vmem outstanding -> cheap
    }
    // ---- super-step boundary: prefetch next x chunk, flush out rings ----
    const int t0 = c * 16;
    const bool more = (c + 1 < 32);
    float4 nx0, nx1, nx2, nx3, nx4, nx5;
    if (more) {
      const float4* src = (const float4*)(xbase + (size_t)(c + 1) * 16 * H3);
      nx0 = src[tid + 0 * 512]; nx1 = src[tid + 1 * 512];
      nx2 = src[tid + 2 * 512]; nx3 = src[tid + 3 * 512];
      nx4 = src[tid + 4 * 512]; nx5 = src[tid + 5 * 512];
    }
    {  // flush f16 ring: 512 threads x one f16x8
      int s = tid >> 5, j8 = (tid & 31) * 8;
      *(f16x8*)(orow16 + (size_t)(t0 + s) * HH + j8) = *(const f16x8*)&ring16[s][j8];
    }
    if (wf32) {  // flush fp32 ring: 512 threads x two float4
#pragma unroll
      for (int k = 0; k < 2; ++k) {
        int idx = tid + k * 512;
        int s = idx >> 6, j4 = (idx & 63) * 4;
        *(float4*)(orow + (size_t)(t0 + s) * HH + j4) = *(const float4*)&ring32[s][j4];
      }
    }
    if (more) {
      float4* xd = (float4*)xs;
      xd[tid + 0 * 512] = nx0; xd[tid + 1 * 512] = nx1;
      xd[tid + 2 * 512] = nx2; xd[tid + 3 * 512] = nx3;
      xd[tid + 4 * 512] = nx4; xd[tid + 5 * 512] = nx5;
    }
    __syncthreads();  // one vmem drain per 16 steps
  }
}

// ---------------- gat_W transpose -> f16: [4,256,64] -> [256 cols][256 k] --
__global__ void gat_wt(const float* __restrict__ W, half_t* __restrict__ Wt) {
  int idx = blockIdx.x * 256 + threadIdx.x;  // [0, 65536)
  int col = idx >> 8, k = idx & 255;
  Wt[idx] = (half_t)W[((size_t)((col >> 6) * HH + k)) * HDIM + (col & 63)];
}

// ---------------- GAT f_src/f_dst ----------------
__global__ void gat_fsd(const float* __restrict__ hgat, const float* __restrict__ a,
                        float* __restrict__ fsrc, float* __restrict__ fdst) {
  int b = blockIdx.x, hd = blockIdx.y, t = threadIdx.x;  // block 512
  const float* hp = hgat + ((size_t)(b * TT + t)) * HH + hd * HDIM;
  const float* ap = a + hd * 2 * HDIM;
  float fs = 0.f, fd = 0.f;
#pragma unroll 4
  for (int d = 0; d < HDIM; ++d) {
    float hv = hp[d];
    fs += hv * ap[d];
    fd += hv * ap[HDIM + d];
  }
  fsrc[(b * NHEADS + hd) * TT + t] = fs;
  fdst[(b * NHEADS + hd) * TT + t] = fd;
}

// ---------------- GAT flash attention ----------------
__global__ __launch_bounds__(256) void gat_attn(
    const float* __restrict__ hgat, const float* __restrict__ fsrc,
    const float* __restrict__ fdst, float* __restrict__ out) {
  __shared__ __align__(16) float Ht[128][64];
  __shared__ __align__(16) float fd[128];
  __shared__ __align__(16) float pq[4][128][8];
  const int tid = threadIdx.x, wave = tid >> 6, lane = tid & 63;
  const int hd = blockIdx.y, b = blockIdx.z;
  const int i0 = blockIdx.x * 32 + wave * 8;
  const float* fs = fsrc + (size_t)(b * NHEADS + hd) * TT;
  const float* fdp = fdst + (size_t)(b * NHEADS + hd) * TT;
  float m[8], l[8], acc[8], fi[8];
#pragma unroll
  for (int q = 0; q < 8; ++q) { m[q] = -1e30f; l[q] = 0.f; acc[q] = 0.f; fi[q] = fs[i0 + q]; }
  for (int jt = 0; jt < TT; jt += 128) {
#pragma unroll
    for (int u = 0; u < 8; ++u) {
      int idx = tid + u * 256;
      int jj = idx >> 4, dq = (idx & 15) * 4;
      *(float4*)&Ht[jj][dq] =
          *(const float4*)&hgat[((size_t)(b * TT + jt + jj)) * HH + hd * HDIM + dq];
    }
    if (tid < 128) fd[tid] = fdp[jt + tid];
    __syncthreads();
#pragma unroll
    for (int q = 0; q < 8; ++q) {
      float e0 = fi[q] + fd[lane];      e0 = (e0 > 0.f) ? e0 : 0.2f * e0;
      float e1 = fi[q] + fd[lane + 64]; e1 = (e1 > 0.f) ? e1 : 0.2f * e1;
      float mn = fmaxf(m[q], wmax(fmaxf(e0, e1)));
      float corr = __expf(m[q] - mn);
      float p0 = __expf(e0 - mn), p1 = __expf(e1 - mn);
      l[q] = l[q] * corr + wsum(p0 + p1);
      m[q] = mn;
      acc[q] *= corr;
      pq[wave][lane][q] = p0;
      pq[wave][lane + 64][q] = p1;
    }
#pragma unroll 4
    for (int jj = 0; jj < 128; ++jj) {
      float4 pa = *(const float4*)&pq[wave][jj][0];
      float4 pb = *(const float4*)&pq[wave][jj][4];
      float hv = Ht[jj][lane];
      acc[0] += pa.x * hv; acc[1] += pa.y * hv; acc[2] += pa.z * hv; acc[3] += pa.w * hv;
      acc[4] += pb.x * hv; acc[5] += pb.y * hv; acc[6] += pb.z * hv; acc[7] += pb.w * hv;
    }
    __syncthreads();
  }
#pragma unroll
  for (int q = 0; q < 8; ++q)
    out[((size_t)(b * TT + i0 + q)) * HH + hd * HDIM + lane] = acc[q] / l[q];
}

// ---------------- residual + LayerNorm (f16 output for MFMA GEMM) ---------
__global__ __launch_bounds__(256) void ln_res(
    const float* __restrict__ g, const float* __restrict__ gat,
    const float* __restrict__ gamma, const float* __restrict__ beta,
    half_t* __restrict__ y16) {
  int wave = threadIdx.x >> 6, lane = threadIdx.x & 63;
  size_t n = (size_t)blockIdx.x * 4 + wave;
  float4 v = ((const float4*)(g + n * HH))[lane];
  float4 w = ((const float4*)(gat + n * HH))[lane];
  v.x += w.x; v.y += w.y; v.z += w.z; v.w += w.w;
  float mu = wsum(v.x + v.y + v.z + v.w) * (1.f / 256.f);
  float dx = v.x - mu, dy = v.y - mu, dz = v.z - mu, dw = v.w - mu;
  float var = wsum(dx * dx + dy * dy + dz * dz + dw * dw) * (1.f / 256.f);
  float rstd = rsqrtf(var + 1e-5f);
  float4 gm = ((const float4*)gamma)[lane];
  float4 bt = ((const float4*)beta)[lane];
  half4_t o = {(half_t)(dx * rstd * gm.x + bt.x), (half_t)(dy * rstd * gm.y + bt.y),
               (half_t)(dz * rstd * gm.z + bt.z), (half_t)(dw * rstd * gm.w + bt.w)};
  ((half4_t*)(y16 + n * HH))[lane] = o;
}

// ---------------- MHA flash attention (f16 ctx output) --------------------
__global__ __launch_bounds__(256) void mha_attn(const float* __restrict__ qkv,
                                                half_t* __restrict__ ctx16) {
  __shared__ __align__(16) float KV[8320];        // K^T [64][130] | V [128][64]
  __shared__ __align__(16) float qq[4][64][8];
  __shared__ __align__(16) float pq[4][128][8];
  const int tid = threadIdx.x, wave = tid >> 6, lane = tid & 63;
  const int hd = blockIdx.y, b = blockIdx.z;
  const int i0 = blockIdx.x * 32 + wave * 8;
#pragma unroll
  for (int q = 0; q < 8; ++q)
    qq[wave][lane][q] = qkv[((size_t)(b * TT + i0 + q)) * H3 + hd * HDIM + lane];
  float m[8], l[8], acc[8];
#pragma unroll
  for (int q = 0; q < 8; ++q) { m[q] = -1e30f; l[q] = 0.f; acc[q] = 0.f; }
  for (int jt = 0; jt < TT; jt += 128) {
    // stage K^T: KV[dd*130 + j]
#pragma unroll
    for (int u = 0; u < 8; ++u) {
      int idx = tid + u * 256;
      int jj = idx >> 4, dq = (idx & 15) * 4;
      float4 kv = *(const float4*)&qkv[((size_t)(b * TT + jt + jj)) * H3 + HH + hd * HDIM + dq];
      KV[(dq + 0) * 130 + jj] = kv.x;
      KV[(dq + 1) * 130 + jj] = kv.y;
      KV[(dq + 2) * 130 + jj] = kv.z;
      KV[(dq + 3) * 130 + jj] = kv.w;
    }
    __syncthreads();
    float e0[8] = {}, e1[8] = {};
#pragma unroll 8
    for (int dd = 0; dd < 64; ++dd) {
      float4 qa = *(const float4*)&qq[wave][dd][0];
      float4 qb = *(const float4*)&qq[wave][dd][4];
      float k0 = KV[dd * 130 + lane], k1 = KV[dd * 130 + 64 + lane];
      e0[0] += qa.x * k0; e0[1] += qa.y * k0; e0[2] += qa.z * k0; e0[3] += qa.w * k0;
      e0[4] += qb.x * k0; e0[5] += qb.y * k0; e0[6] += qb.z * k0; e0[7] += qb.w * k0;
      e1[0] += qa.x * k1; e1[1] += qa.y * k1; e1[2] += qa.z * k1; e1[3] += qa.w * k1;
      e1[4] += qb.x * k1; e1[5] += qb.y * k1; e1[6] += qb.z * k1; e1[7] += qb.w * k1;
    }
    __syncthreads();  // done reading K^T
    // stage V over the same buffer: KV[j*64 + dd]
#pragma unroll
    for (int u = 0; u < 8; ++u) {
      int idx = tid + u * 256;
      int jj = idx >> 4, dq = (idx & 15) * 4;
      *(float4*)&KV[jj * 64 + dq] =
          *(const float4*)&qkv[((size_t)(b * TT + jt + jj)) * H3 + 2 * HH + hd * HDIM + dq];
    }
#pragma unroll
    for (int q = 0; q < 8; ++q) {
      float s0 = e0[q] * 0.125f, s1 = e1[q] * 0.125f;
      float mn = fmaxf(m[q], wmax(fmaxf(s0, s1)));
      float corr = __expf(m[q] - mn);
      float p0 = __expf(s0 - mn), p1 = __expf(s1 - mn);
      l[q] = l[q] * corr + wsum(p0 + p1);
      m[q] = mn;
      acc[q] *= corr;
      pq[wave][lane][q] = p0;
      pq[wave][lane + 64][q] = p1;
    }
    __syncthreads();  // V staged, pq written
#pragma unroll 4
    for (int jj = 0; jj < 128; ++jj) {
      float4 pa = *(const float4*)&pq[wave][jj][0];
      float4 pb = *(const float4*)&pq[wave][jj][4];
      float hv = KV[jj * 64 + lane];
      acc[0] += pa.x * hv; acc[1] += pa.y * hv; acc[2] += pa.z * hv; acc[3] += pa.w * hv;
      acc[4] += pb.x * hv; acc[5] += pb.y * hv; acc[6] += pb.z * hv; acc[7] += pb.w * hv;
    }
    __syncthreads();  // before next K^T overwrite
  }
#pragma unroll
  for (int q = 0; q < 8; ++q)
    ctx16[((size_t)(b * TT + i0 + q)) * HH + hd * HDIM + lane] = (half_t)(acc[q] / l[q]);
}

// ---------------- mean pool over T ----------------
__global__ void mean_pool(const float* __restrict__ x, float* __restrict__ out) {
  int b = blockIdx.x, j = threadIdx.x;
  const float* p = x + (size_t)b * TT * HH + j;
  float s = 0.f;
  for (int t = 0; t < TT; ++t) s += p[(size_t)t * HH];
  out[b * HH + j] = s * (1.f / 512.f);
}

// ---------------- FC layers ----------------
__global__ void fc1_k(const float* __restrict__ pooled, const float* __restrict__ w,
                      const float* __restrict__ bias, float* __restrict__ hid) {
  int b = blockIdx.x, o = threadIdx.x;  // 128 threads
  const float* pp = pooled + b * HH;
  const float* wp = w + o * HH;
  float s = 0.f;
#pragma unroll 4
  for (int k = 0; k < HH; ++k) s += pp[k] * wp[k];
  hid[b * 128 + o] = fmaxf(s + bias[o], 0.f);
}

__global__ void fc2_k(const float* __restrict__ hid, const float* __restrict__ w,
                      const float* __restrict__ bias, float* __restrict__ out) {
  int t = threadIdx.x;  // 256 = 32 m x 8 c
  int mm = t >> 3, c = t & 7;
  const float* hp = hid + mm * 128;
  const float* wp = w + c * 128;
  float s = 0.f;
#pragma unroll 4
  for (int k = 0; k < 128; ++k) s += hp[k] * wp[k];
  out[mm * 8 + c] = s + bias[c];
}

extern "C" void kernel_launch(void* const* d_in, const int* in_sizes, int n_in,
                              void* d_out, int out_size, void* d_ws, size_t ws_size,
                              hipStream_t stream) {
  (void)in_sizes; (void)n_in; (void)out_size; (void)ws_size;
  const float* x    = (const float*)d_in[0];
  const float* Wih0 = (const float*)d_in[1];
  const float* Whh0 = (const float*)d_in[2];
  const float* bih0 = (const float*)d_in[3];
  const float* bhh0 = (const float*)d_in[4];
  const float* Wih1 = (const float*)d_in[5];
  const float* Whh1 = (const float*)d_in[6];
  const float* bih1 = (const float*)d_in[7];
  const float* bhh1 = (const float*)d_in[8];
  const float* gatW = (const float*)d_in[9];
  const float* gatA = (const float*)d_in[10];
  const float* lng  = (const float*)d_in[11];
  const float* lnb  = (const float*)d_in[12];
  const float* inw  = (const float*)d_in[13];
  const float* inb  = (const float*)d_in[14];
  const float* outw = (const float*)d_in[15];
  const float* outb = (const float*)d_in[16];
  const float* f1w  = (const float*)d_in[17];
  const float* f1b  = (const float*)d_in[18];
  const float* f2w  = (const float*)d_in[19];
  const float* f2b  = (const float*)d_in[20];
  float* out = (float*)d_out;
  float* ws = (float*)d_ws;

  // fp32 regions:
  float* XPA   = ws;                  // 16384*768: xp0 -> xp1 -> qkv
  float* G0    = ws + 12582912;       // gat_out (gru0 fp32 h never stored)
  float* G1    = G0 + 4194304;        // gru1-out (fp32, for ln_res)
  float* Yb    = G1 + 4194304;        // [f16 G0_16 | f16 G1_16] -> attn_out fp32
  float* HGAT  = Yb + 4194304;        // gat feats fp32 -> [f16 CTX16 | f16 Y16]
  float* GATWTf= HGAT + 4194304;
  float* FSRC  = GATWTf + 65536;
  float* FDST  = FSRC + 65536;
  float* POOL  = FDST + 65536;
  float* HIDb  = POOL + 8192;
  float* W16b  = HIDb + 4096;         // f16 weight pool (~1.1 MB)

  // f16 aliases (lifetimes verified against launch order):
  half_t* X16     = (half_t*)G1;                   // dead before gru1 writes G1
  half_t* G0_16   = (half_t*)Yb;                   // dead before attn_out write
  half_t* G1_16   = (half_t*)(Yb + 2097152);
  half_t* CTX16   = (half_t*)HGAT;                 // written after gat phase done
  half_t* Y16     = (half_t*)(HGAT + 2097152);
  half_t* GATWT16 = (half_t*)GATWTf;
  half_t* W16ih0  = (half_t*)W16b;
  half_t* W16ih1  = (half_t*)(W16b + 49152);
  half_t* W16in   = (half_t*)(W16b + 49152 + 98304);
  half_t* W16out  = (half_t*)(W16b + 49152 + 98304 + 98304);

  // 0. casts (weights once; x once)
  castk<<<2048, 256, 0, stream>>>(x, X16, 2097152);
  castk<<<96, 256, 0, stream>>>(Wih0, W16ih0, 98304);
  castk<<<192, 256, 0, stream>>>(Wih1, W16ih1, 196608);
  castk<<<192, 256, 0, stream>>>(inw, W16in, 196608);
  castk<<<64, 256, 0, stream>>>(outw, W16out, 65536);
  gat_wt<<<256, 256, 0, stream>>>(gatW, GATWT16);
  // 1. xp0 = x @ W_ih0^T + b_ih0   (MFMA f16)
  gemm_f16<<<dim3(12, 128), 256, 0, stream>>>(X16, W16ih0, bih0, XPA, 16384, 768, 128);
  // 2. GRU layer 0 (fp32 h not needed -> nullptr)
  gru_layer<<<32, 512, 0, stream>>>(XPA, Whh0, bhh0, nullptr, G0_16);
  // 3. xp1 = g0 @ W_ih1^T + b_ih1
  gemm_f16<<<dim3(12, 128), 256, 0, stream>>>(G0_16, W16ih1, bih1, XPA, 16384, 768, 256);
  // 4. GRU layer 1
  gru_layer<<<32, 512, 0, stream>>>(XPA, Whh1, bhh1, G1, G1_16);
  // 5. GAT per-head features + attention
  gemm_f16<<<dim3(4, 128), 256, 0, stream>>>(G1_16, GATWT16, nullptr, HGAT, 16384, 256, 256);
  gat_fsd<<<dim3(32, 4), 512, 0, stream>>>(HGAT, gatA, FSRC, FDST);
  gat_attn<<<dim3(16, 4, 32), 256, 0, stream>>>(HGAT, FSRC, FDST, G0);
  // 6. y = LN(g + gat_out) -> f16
  ln_res<<<4096, 256, 0, stream>>>(G1, G0, lng, lnb, Y16);
  // 7. MHA
  gemm_f16<<<dim3(12, 128), 256, 0, stream>>>(Y16, W16in, inb, XPA, 16384, 768, 256);
  mha_attn<<<dim3(16, 4, 32), 256, 0, stream>>>(XPA, CTX16);
  gemm_f16<<<dim3(4, 128), 256, 0, stream>>>(CTX16, W16out, outb, Yb, 16384, 256, 256);
  // 8. pool + FC head
  mean_pool<<<32, 256, 0, stream>>>(Yb, POOL);
  fc1_k<<<32, 128, 0, stream>>>(POOL, f1w, f1b, HIDb);
  fc2_k<<<1, 256, 0, stream>>>(HIDb, f2w, f2b, out);
}

// Round 4
// 1992.864 us; speedup vs baseline: 1.2218x; 1.0337x over previous
//
#include <hip/hip_runtime.h>
#include <math.h>

// Problem constants
#define BB 32
#define TT 512
#define INF_ 128
#define HH 256
#define H3 768
#define NHEADS 4
#define HDIM 64

typedef _Float16 half_t;
typedef half_t half2_t __attribute__((ext_vector_type(2)));
typedef half_t half4_t __attribute__((ext_vector_type(4)));
typedef half_t f16x8 __attribute__((ext_vector_type(8)));
typedef float f32x4 __attribute__((ext_vector_type(4)));

// ---------------- wave helpers (wave = 64 on CDNA) ----------------
__device__ __forceinline__ float wsum(float v) {
#pragma unroll
  for (int o = 32; o > 0; o >>= 1) v += __shfl_xor(v, o, 64);
  return v;
}
__device__ __forceinline__ float wmax(float v) {
#pragma unroll
  for (int o = 32; o > 0; o >>= 1) v = fmaxf(v, __shfl_xor(v, o, 64));
  return v;
}

// ---------------- fp32 -> f16 cast (n % 1024 == 0) ----------------
__global__ void castk(const float* __restrict__ s, half_t* __restrict__ d, int n) {
  int i = (blockIdx.x * 256 + threadIdx.x) * 4;
  if (i < n) {
    float4 v = *(const float4*)(s + i);
    half4_t o = {(half_t)v.x, (half_t)v.y, (half_t)v.z, (half_t)v.w};
    *(half4_t*)(d + i) = o;
  }
}

// ---------------- MFMA f16 GEMM: C[M,N] = A[M,K] * B[N,K]^T + bias -------
__global__ __launch_bounds__(256) void gemm_f16(
    const half_t* __restrict__ A, const half_t* __restrict__ B,
    const float* __restrict__ bias, float* __restrict__ C,
    int M, int N, int K) {
  __shared__ __align__(16) half_t As[128][40];
  __shared__ __align__(16) half_t Bs[64][40];
  const int tid = threadIdx.x;
  const int wave = tid >> 6, lane = tid & 63;
  const int m0 = blockIdx.y * 128, n0 = blockIdx.x * 64;
  const int mrow = lane & 15, quad = lane >> 4;
  f32x4 acc00 = {0.f, 0.f, 0.f, 0.f}, acc01 = acc00, acc02 = acc00, acc03 = acc00;
  f32x4 acc10 = acc00, acc11 = acc00, acc12 = acc00, acc13 = acc00;
  for (int k0 = 0; k0 < K; k0 += 32) {
    __syncthreads();  // previous iter's fragments consumed
#pragma unroll
    for (int u = 0; u < 2; ++u) {  // stage A: 128 rows x 32 halfs
      int idx = tid + u * 256;
      int row = idx >> 2, seg = idx & 3;
      *(f16x8*)&As[row][seg * 8] =
          *(const f16x8*)&A[(size_t)(m0 + row) * K + k0 + seg * 8];
    }
    {  // stage B: 64 rows x 32 halfs
      int row = tid >> 2, seg = tid & 3;
      *(f16x8*)&Bs[row][seg * 8] =
          *(const f16x8*)&B[(size_t)(n0 + row) * K + k0 + seg * 8];
    }
    __syncthreads();
    f16x8 af0 = *(const f16x8*)&As[wave * 32 + mrow][quad * 8];
    f16x8 af1 = *(const f16x8*)&As[wave * 32 + 16 + mrow][quad * 8];
    f16x8 bf0 = *(const f16x8*)&Bs[mrow][quad * 8];
    f16x8 bf1 = *(const f16x8*)&Bs[16 + mrow][quad * 8];
    f16x8 bf2 = *(const f16x8*)&Bs[32 + mrow][quad * 8];
    f16x8 bf3 = *(const f16x8*)&Bs[48 + mrow][quad * 8];
    acc00 = __builtin_amdgcn_mfma_f32_16x16x32_f16(af0, bf0, acc00, 0, 0, 0);
    acc01 = __builtin_amdgcn_mfma_f32_16x16x32_f16(af0, bf1, acc01, 0, 0, 0);
    acc02 = __builtin_amdgcn_mfma_f32_16x16x32_f16(af0, bf2, acc02, 0, 0, 0);
    acc03 = __builtin_amdgcn_mfma_f32_16x16x32_f16(af0, bf3, acc03, 0, 0, 0);
    acc10 = __builtin_amdgcn_mfma_f32_16x16x32_f16(af1, bf0, acc10, 0, 0, 0);
    acc11 = __builtin_amdgcn_mfma_f32_16x16x32_f16(af1, bf1, acc11, 0, 0, 0);
    acc12 = __builtin_amdgcn_mfma_f32_16x16x32_f16(af1, bf2, acc12, 0, 0, 0);
    acc13 = __builtin_amdgcn_mfma_f32_16x16x32_f16(af1, bf3, acc13, 0, 0, 0);
  }
  float bv0 = bias ? bias[n0 + mrow] : 0.f;
  float bv1 = bias ? bias[n0 + 16 + mrow] : 0.f;
  float bv2 = bias ? bias[n0 + 32 + mrow] : 0.f;
  float bv3 = bias ? bias[n0 + 48 + mrow] : 0.f;
  const int rb = m0 + wave * 32 + quad * 4;
#pragma unroll
  for (int r = 0; r < 4; ++r) {
    float* c0 = C + (size_t)(rb + r) * N + n0;
    c0[mrow] = acc00[r] + bv0;
    c0[16 + mrow] = acc01[r] + bv1;
    c0[32 + mrow] = acc02[r] + bv2;
    c0[48 + mrow] = acc03[r] + bv3;
    float* c1 = C + (size_t)(rb + 16 + r) * N + n0;
    c1[mrow] = acc10[r] + bv0;
    c1[16 + mrow] = acc11[r] + bv1;
    c1[32 + mrow] = acc12[r] + bv2;
    c1[48 + mrow] = acc13[r] + bv3;
  }
}

// ---------------- GRU recurrence: MFMA GEMV, spill-free register budget ---
// R3 post-mortem: active-CU VALUBusy 38% (~600 extra VALU insts/wave/step)
// = spill/reload machinery. 48 resident frags (192 regs) + 16 a-regs + 12
// acc + overhead ~250 > 256 budget (512thr, 2 waves/SIMD) -> scratch spill,
// L2-resident (invisible in FETCH_SIZE) but eats the VALU pipe every step.
// R4: buy back ~45 regs so true need ~215 << 256:
//  - 8 of 48 weight frags (z,n gates, k-tiles 6,7) live in LDS (64 KB),
//    read per step as contiguous conflict-free ds_read_b128 (overlaps MFMA).
//  - k-outer loop: ONE streamed a-frag (4 regs) x 6 live accs (dep spacing
//    6 >= MFMA acc-reuse latency), replacing 16 a-regs + 2 sequential passes.
//  - no step-loop unroll (halves live ranges).
// Inner loop still touches NO global memory (x staged per 16 steps, outputs
// ring-buffered) so the single per-step barrier has vmcnt==0.
__device__ __forceinline__ f16x8 ldw8(const float* p) {
  float4 a = *(const float4*)p;
  float4 b = *(const float4*)(p + 4);
  return f16x8{(half_t)a.x, (half_t)a.y, (half_t)a.z, (half_t)a.w,
               (half_t)b.x, (half_t)b.y, (half_t)b.z, (half_t)b.w};
}

#define GDECL6(g) f16x8 g##0, g##1, g##2, g##3, g##4, g##5;
#define GDECL8(g) f16x8 g##0, g##1, g##2, g##3, g##4, g##5, g##6, g##7;
#define GLOAD6(g, base)            \
  {                                \
    const float* _p = (base);      \
    g##0 = ldw8(_p + 0 * 32);      \
    g##1 = ldw8(_p + 1 * 32);      \
    g##2 = ldw8(_p + 2 * 32);      \
    g##3 = ldw8(_p + 3 * 32);      \
    g##4 = ldw8(_p + 4 * 32);      \
    g##5 = ldw8(_p + 5 * 32);      \
  }
#define GLOAD8(g, base)            \
  {                                \
    const float* _p = (base);      \
    g##0 = ldw8(_p + 0 * 32);      \
    g##1 = ldw8(_p + 1 * 32);      \
    g##2 = ldw8(_p + 2 * 32);      \
    g##3 = ldw8(_p + 3 * 32);      \
    g##4 = ldw8(_p + 4 * 32);      \
    g##5 = ldw8(_p + 5 * 32);      \
    g##6 = ldw8(_p + 6 * 32);      \
    g##7 = ldw8(_p + 7 * 32);      \
  }
// 6 MFMAs sharing one a-frag; same-acc dependency spacing = 6
#define MQ6(a, R0, R1, Z0, Z1, N0, N1)                                  \
  aR0 = __builtin_amdgcn_mfma_f32_16x16x32_f16(a, R0, aR0, 0, 0, 0);    \
  aR1 = __builtin_amdgcn_mfma_f32_16x16x32_f16(a, R1, aR1, 0, 0, 0);    \
  aZ0 = __builtin_amdgcn_mfma_f32_16x16x32_f16(a, Z0, aZ0, 0, 0, 0);    \
  aZ1 = __builtin_amdgcn_mfma_f32_16x16x32_f16(a, Z1, aZ1, 0, 0, 0);    \
  aN0 = __builtin_amdgcn_mfma_f32_16x16x32_f16(a, N0, aN0, 0, 0, 0);    \
  aN1 = __builtin_amdgcn_mfma_f32_16x16x32_f16(a, N1, aN1, 0, 0, 0);
#define LDH(k) (*(const f16x8*)(hb + (k) * 32))
#define RW(s) (*(const f16x8*)(wb + (s) * 512))

__global__ __launch_bounds__(512, 2) void gru_layer(
    const float* __restrict__ xp, const float* __restrict__ Whh,
    const float* __restrict__ bhh, float* __restrict__ out,
    half_t* __restrict__ out16) {
  __shared__ __align__(16) float xs[16 * H3];          // 48 KB x-proj chunk
  __shared__ __align__(16) half_t hs[2][256];          // 1 KB h ping-pong
  __shared__ __align__(16) half_t ring16[16][256];     // 8 KB f16 out ring
  __shared__ __align__(16) float ring32[16][256];      // 16 KB fp32 out ring
  __shared__ __align__(16) half_t wlds[8][8][512];     // 64 KB LDS weight frags
  const int tid = threadIdx.x;
  const int w = tid >> 6, lane = tid & 63;
  const int col = lane & 15, quad = lane >> 4;
  const int u0 = 32 * w + col, u1 = u0 + 16;  // this lane's 2 hidden units
  const int b = blockIdx.x;
  const bool wf32 = (out != nullptr);  // uniform: layer 0 skips fp32 h-store

  // Register-resident weight fragments (40 frags = 160 regs):
  //   wr: k-tiles 0..7 (both unit tiles); wz,wn: k-tiles 0..5.
  GDECL8(wr0_) GDECL8(wr1_)
  GDECL6(wz0_) GDECL6(wz1_)
  GDECL6(wn0_) GDECL6(wn1_)
  GLOAD8(wr0_, Whh + (size_t)u0 * HH + quad * 8)
  GLOAD8(wr1_, Whh + (size_t)u1 * HH + quad * 8)
  GLOAD6(wz0_, Whh + (size_t)(HH + u0) * HH + quad * 8)
  GLOAD6(wz1_, Whh + (size_t)(HH + u1) * HH + quad * 8)
  GLOAD6(wn0_, Whh + (size_t)(2 * HH + u0) * HH + quad * 8)
  GLOAD6(wn1_, Whh + (size_t)(2 * HH + u1) * HH + quad * 8)
  // LDS-resident frags: k-tiles 6,7 of z,n (8 frags = 8 KB/wave, 64 KB total)
  {
    const float* bz = Whh + (size_t)(HH + u0) * HH + quad * 8;
    const float* bz1p = Whh + (size_t)(HH + u1) * HH + quad * 8;
    const float* bn = Whh + (size_t)(2 * HH + u0) * HH + quad * 8;
    const float* bn1p = Whh + (size_t)(2 * HH + u1) * HH + quad * 8;
    *(f16x8*)&wlds[w][0][lane * 8] = ldw8(bz + 6 * 32);
    *(f16x8*)&wlds[w][1][lane * 8] = ldw8(bz1p + 6 * 32);
    *(f16x8*)&wlds[w][2][lane * 8] = ldw8(bn + 6 * 32);
    *(f16x8*)&wlds[w][3][lane * 8] = ldw8(bn1p + 6 * 32);
    *(f16x8*)&wlds[w][4][lane * 8] = ldw8(bz + 7 * 32);
    *(f16x8*)&wlds[w][5][lane * 8] = ldw8(bz1p + 7 * 32);
    *(f16x8*)&wlds[w][6][lane * 8] = ldw8(bn + 7 * 32);
    *(f16x8*)&wlds[w][7][lane * 8] = ldw8(bn1p + 7 * 32);
  }
  const half_t* wb = &wlds[w][0][lane * 8];
  const float br0 = bhh[u0], bz0 = bhh[HH + u0], bn0 = bhh[2 * HH + u0];
  const float br1 = bhh[u1], bz1 = bhh[HH + u1], bn1 = bhh[2 * HH + u1];
  float hprev0 = 0.f, hprev1 = 0.f;

  const float* xbase = xp + (size_t)b * TT * H3;
  half_t* orow16 = out16 + (size_t)b * TT * HH;
  float* orow = wf32 ? (out + (size_t)b * TT * HH) : nullptr;

  // prologue: stage chunk 0, zero h
  {
    const float4* src = (const float4*)xbase;
    float4* xd = (float4*)xs;
#pragma unroll
    for (int k = 0; k < 6; ++k) xd[tid + k * 512] = src[tid + k * 512];
  }
  if (tid < 256) hs[0][tid] = (half_t)0.f;
  __syncthreads();

  for (int c = 0; c < 32; ++c) {  // 32 super-steps x 16 steps
    for (int tt = 0; tt < 16; ++tt) {
      const half_t* hb = &hs[tt & 1][quad * 8];
      f32x4 aR0 = {0.f, 0.f, 0.f, 0.f}, aZ0 = aR0, aN0 = aR0;
      f32x4 aR1 = aR0, aZ1 = aR0, aN1 = aR0;
      {
        f16x8 ak = LDH(0);
        MQ6(ak, wr0_0, wr1_0, wz0_0, wz1_0, wn0_0, wn1_0)
      }
      {
        f16x8 ak = LDH(1);
        MQ6(ak, wr0_1, wr1_1, wz0_1, wz1_1, wn0_1, wn1_1)
      }
      {
        f16x8 ak = LDH(2);
        MQ6(ak, wr0_2, wr1_2, wz0_2, wz1_2, wn0_2, wn1_2)
      }
      {
        f16x8 ak = LDH(3);
        MQ6(ak, wr0_3, wr1_3, wz0_3, wz1_3, wn0_3, wn1_3)
      }
      {
        f16x8 ak = LDH(4);
        MQ6(ak, wr0_4, wr1_4, wz0_4, wz1_4, wn0_4, wn1_4)
      }
      {
        f16x8 ak = LDH(5);
        MQ6(ak, wr0_5, wr1_5, wz0_5, wz1_5, wn0_5, wn1_5)
      }
      {
        f16x8 ak = LDH(6);
        f16x8 z0 = RW(0), z1 = RW(1), n0 = RW(2), n1 = RW(3);
        MQ6(ak, wr0_6, wr1_6, z0, z1, n0, n1)
      }
      {
        f16x8 ak = LDH(7);
        f16x8 z0 = RW(4), z1 = RW(5), n0 = RW(6), n1 = RW(7);
        MQ6(ak, wr0_7, wr1_7, z0, z1, n0, n1)
      }
      const int xb = tt * H3;
      {  // gate for unit u0 (all lanes; quad-redundant)
        float ar = aR0[0], az = aZ0[0], an = aN0[0];
        float xr = xs[xb + u0], xz = xs[xb + 256 + u0], xn = xs[xb + 512 + u0];
        float rg_ = 1.f / (1.f + __expf(-(xr + ar + br0)));
        float zg_ = 1.f / (1.f + __expf(-(xz + az + bz0)));
        float ng_ = 2.f / (1.f + __expf(-2.f * (xn + rg_ * (an + bn0)))) - 1.f;
        float hnew = (1.f - zg_) * ng_ + zg_ * hprev0;
        hprev0 = hnew;
        if (quad == 0) {
          hs[(tt + 1) & 1][u0] = (half_t)hnew;
          ring16[tt][u0] = (half_t)hnew;
          if (wf32) ring32[tt][u0] = hnew;
        }
      }
      {  // gate for unit u1
        float ar = aR1[0], az = aZ1[0], an = aN1[0];
        float xr = xs[xb + u1], xz = xs[xb + 256 + u1], xn = xs[xb + 512 + u1];
        float rg_ = 1.f / (1.f + __expf(-(xr + ar + br1)));
        float zg_ = 1.f / (1.f + __expf(-(xz + az + bz1)));
        float ng_ = 2.f / (1.f + __expf(-2.f * (xn + rg_ * (an + bn1)))) - 1.f;
        float hnew = (1.f - zg_) * ng_ + zg_ * hprev1;
        hprev1 = hnew;
        if (quad == 0) {
          hs[(tt + 1) & 1][u1] = (half_t)hnew;
          ring16[tt][u1] = (half_t)hnew;
          if (wf32) ring32[tt][u1] = hnew;
        }
      }
      __syncthreads();  // h(t+1) visible; no vmem outstanding -> cheap
    }
    // ---- super-step boundary: prefetch next x chunk, flush out rings ----
    const int t0 = c * 16;
    const bool more = (c + 1 < 32);
    float4 nx0, nx1, nx2, nx3, nx4, nx5;
    if (more) {
      const float4* src = (const float4*)(xbase + (size_t)(c + 1) * 16 * H3);
      nx0 = src[tid + 0 * 512]; nx1 = src[tid + 1 * 512];
      nx2 = src[tid + 2 * 512]; nx3 = src[tid + 3 * 512];
      nx4 = src[tid + 4 * 512]; nx5 = src[tid + 5 * 512];
    }
    {  // flush f16 ring: 512 threads x one f16x8
      int s = tid >> 5, j8 = (tid & 31) * 8;
      *(f16x8*)(orow16 + (size_t)(t0 + s) * HH + j8) = *(const f16x8*)&ring16[s][j8];
    }
    if (wf32) {  // flush fp32 ring: 512 threads x two float4
#pragma unroll
      for (int k = 0; k < 2; ++k) {
        int idx = tid + k * 512;
        int s = idx >> 6, j4 = (idx & 63) * 4;
        *(float4*)(orow + (size_t)(t0 + s) * HH + j4) = *(const float4*)&ring32[s][j4];
      }
    }
    if (more) {
      float4* xd = (float4*)xs;
      xd[tid + 0 * 512] = nx0; xd[tid + 1 * 512] = nx1;
      xd[tid + 2 * 512] = nx2; xd[tid + 3 * 512] = nx3;
      xd[tid + 4 * 512] = nx4; xd[tid + 5 * 512] = nx5;
    }
    __syncthreads();  // one vmem drain per 16 steps
  }
}

// ---------------- gat_W transpose -> f16: [4,256,64] -> [256 cols][256 k] --
__global__ void gat_wt(const float* __restrict__ W, half_t* __restrict__ Wt) {
  int idx = blockIdx.x * 256 + threadIdx.x;  // [0, 65536)
  int col = idx >> 8, k = idx & 255;
  Wt[idx] = (half_t)W[((size_t)((col >> 6) * HH + k)) * HDIM + (col & 63)];
}

// ---------------- GAT f_src/f_dst ----------------
__global__ void gat_fsd(const float* __restrict__ hgat, const float* __restrict__ a,
                        float* __restrict__ fsrc, float* __restrict__ fdst) {
  int b = blockIdx.x, hd = blockIdx.y, t = threadIdx.x;  // block 512
  const float* hp = hgat + ((size_t)(b * TT + t)) * HH + hd * HDIM;
  const float* ap = a + hd * 2 * HDIM;
  float fs = 0.f, fd = 0.f;
#pragma unroll 4
  for (int d = 0; d < HDIM; ++d) {
    float hv = hp[d];
    fs += hv * ap[d];
    fd += hv * ap[HDIM + d];
  }
  fsrc[(b * NHEADS + hd) * TT + t] = fs;
  fdst[(b * NHEADS + hd) * TT + t] = fd;
}

// ---------------- GAT flash attention ----------------
__global__ __launch_bounds__(256) void gat_attn(
    const float* __restrict__ hgat, const float* __restrict__ fsrc,
    const float* __restrict__ fdst, float* __restrict__ out) {
  __shared__ __align__(16) float Ht[128][64];
  __shared__ __align__(16) float fd[128];
  __shared__ __align__(16) float pq[4][128][8];
  const int tid = threadIdx.x, wave = tid >> 6, lane = tid & 63;
  const int hd = blockIdx.y, b = blockIdx.z;
  const int i0 = blockIdx.x * 32 + wave * 8;
  const float* fs = fsrc + (size_t)(b * NHEADS + hd) * TT;
  const float* fdp = fdst + (size_t)(b * NHEADS + hd) * TT;
  float m[8], l[8], acc[8], fi[8];
#pragma unroll
  for (int q = 0; q < 8; ++q) { m[q] = -1e30f; l[q] = 0.f; acc[q] = 0.f; fi[q] = fs[i0 + q]; }
  for (int jt = 0; jt < TT; jt += 128) {
#pragma unroll
    for (int u = 0; u < 8; ++u) {
      int idx = tid + u * 256;
      int jj = idx >> 4, dq = (idx & 15) * 4;
      *(float4*)&Ht[jj][dq] =
          *(const float4*)&hgat[((size_t)(b * TT + jt + jj)) * HH + hd * HDIM + dq];
    }
    if (tid < 128) fd[tid] = fdp[jt + tid];
    __syncthreads();
#pragma unroll
    for (int q = 0; q < 8; ++q) {
      float e0 = fi[q] + fd[lane];      e0 = (e0 > 0.f) ? e0 : 0.2f * e0;
      float e1 = fi[q] + fd[lane + 64]; e1 = (e1 > 0.f) ? e1 : 0.2f * e1;
      float mn = fmaxf(m[q], wmax(fmaxf(e0, e1)));
      float corr = __expf(m[q] - mn);
      float p0 = __expf(e0 - mn), p1 = __expf(e1 - mn);
      l[q] = l[q] * corr + wsum(p0 + p1);
      m[q] = mn;
      acc[q] *= corr;
      pq[wave][lane][q] = p0;
      pq[wave][lane + 64][q] = p1;
    }
#pragma unroll 4
    for (int jj = 0; jj < 128; ++jj) {
      float4 pa = *(const float4*)&pq[wave][jj][0];
      float4 pb = *(const float4*)&pq[wave][jj][4];
      float hv = Ht[jj][lane];
      acc[0] += pa.x * hv; acc[1] += pa.y * hv; acc[2] += pa.z * hv; acc[3] += pa.w * hv;
      acc[4] += pb.x * hv; acc[5] += pb.y * hv; acc[6] += pb.z * hv; acc[7] += pb.w * hv;
    }
    __syncthreads();
  }
#pragma unroll
  for (int q = 0; q < 8; ++q)
    out[((size_t)(b * TT + i0 + q)) * HH + hd * HDIM + lane] = acc[q] / l[q];
}

// ---------------- residual + LayerNorm (f16 output for MFMA GEMM) ---------
__global__ __launch_bounds__(256) void ln_res(
    const float* __restrict__ g, const float* __restrict__ gat,
    const float* __restrict__ gamma, const float* __restrict__ beta,
    half_t* __restrict__ y16) {
  int wave = threadIdx.x >> 6, lane = threadIdx.x & 63;
  size_t n = (size_t)blockIdx.x * 4 + wave;
  float4 v = ((const float4*)(g + n * HH))[lane];
  float4 w = ((const float4*)(gat + n * HH))[lane];
  v.x += w.x; v.y += w.y; v.z += w.z; v.w += w.w;
  float mu = wsum(v.x + v.y + v.z + v.w) * (1.f / 256.f);
  float dx = v.x - mu, dy = v.y - mu, dz = v.z - mu, dw = v.w - mu;
  float var = wsum(dx * dx + dy * dy + dz * dz + dw * dw) * (1.f / 256.f);
  float rstd = rsqrtf(var + 1e-5f);
  float4 gm = ((const float4*)gamma)[lane];
  float4 bt = ((const float4*)beta)[lane];
  half4_t o = {(half_t)(dx * rstd * gm.x + bt.x), (half_t)(dy * rstd * gm.y + bt.y),
               (half_t)(dz * rstd * gm.z + bt.z), (half_t)(dw * rstd * gm.w + bt.w)};
  ((half4_t*)(y16 + n * HH))[lane] = o;
}

// ---------------- MHA flash attention (f16 ctx output) --------------------
__global__ __launch_bounds__(256) void mha_attn(const float* __restrict__ qkv,
                                                half_t* __restrict__ ctx16) {
  __shared__ __align__(16) float KV[8320];        // K^T [64][130] | V [128][64]
  __shared__ __align__(16) float qq[4][64][8];
  __shared__ __align__(16) float pq[4][128][8];
  const int tid = threadIdx.x, wave = tid >> 6, lane = tid & 63;
  const int hd = blockIdx.y, b = blockIdx.z;
  const int i0 = blockIdx.x * 32 + wave * 8;
#pragma unroll
  for (int q = 0; q < 8; ++q)
    qq[wave][lane][q] = qkv[((size_t)(b * TT + i0 + q)) * H3 + hd * HDIM + lane];
  float m[8], l[8], acc[8];
#pragma unroll
  for (int q = 0; q < 8; ++q) { m[q] = -1e30f; l[q] = 0.f; acc[q] = 0.f; }
  for (int jt = 0; jt < TT; jt += 128) {
    // stage K^T: KV[dd*130 + j]
#pragma unroll
    for (int u = 0; u < 8; ++u) {
      int idx = tid + u * 256;
      int jj = idx >> 4, dq = (idx & 15) * 4;
      float4 kv = *(const float4*)&qkv[((size_t)(b * TT + jt + jj)) * H3 + HH + hd * HDIM + dq];
      KV[(dq + 0) * 130 + jj] = kv.x;
      KV[(dq + 1) * 130 + jj] = kv.y;
      KV[(dq + 2) * 130 + jj] = kv.z;
      KV[(dq + 3) * 130 + jj] = kv.w;
    }
    __syncthreads();
    float e0[8] = {}, e1[8] = {};
#pragma unroll 8
    for (int dd = 0; dd < 64; ++dd) {
      float4 qa = *(const float4*)&qq[wave][dd][0];
      float4 qb = *(const float4*)&qq[wave][dd][4];
      float k0 = KV[dd * 130 + lane], k1 = KV[dd * 130 + 64 + lane];
      e0[0] += qa.x * k0; e0[1] += qa.y * k0; e0[2] += qa.z * k0; e0[3] += qa.w * k0;
      e0[4] += qb.x * k0; e0[5] += qb.y * k0; e0[6] += qb.z * k0; e0[7] += qb.w * k0;
      e1[0] += qa.x * k1; e1[1] += qa.y * k1; e1[2] += qa.z * k1; e1[3] += qa.w * k1;
      e1[4] += qb.x * k1; e1[5] += qb.y * k1; e1[6] += qb.z * k1; e1[7] += qb.w * k1;
    }
    __syncthreads();  // done reading K^T
    // stage V over the same buffer: KV[j*64 + dd]
#pragma unroll
    for (int u = 0; u < 8; ++u) {
      int idx = tid + u * 256;
      int jj = idx >> 4, dq = (idx & 15) * 4;
      *(float4*)&KV[jj * 64 + dq] =
          *(const float4*)&qkv[((size_t)(b * TT + jt + jj)) * H3 + 2 * HH + hd * HDIM + dq];
    }
#pragma unroll
    for (int q = 0; q < 8; ++q) {
      float s0 = e0[q] * 0.125f, s1 = e1[q] * 0.125f;
      float mn = fmaxf(m[q], wmax(fmaxf(s0, s1)));
      float corr = __expf(m[q] - mn);
      float p0 = __expf(s0 - mn), p1 = __expf(s1 - mn);
      l[q] = l[q] * corr + wsum(p0 + p1);
      m[q] = mn;
      acc[q] *= corr;
      pq[wave][lane][q] = p0;
      pq[wave][lane + 64][q] = p1;
    }
    __syncthreads();  // V staged, pq written
#pragma unroll 4
    for (int jj = 0; jj < 128; ++jj) {
      float4 pa = *(const float4*)&pq[wave][jj][0];
      float4 pb = *(const float4*)&pq[wave][jj][4];
      float hv = KV[jj * 64 + lane];
      acc[0] += pa.x * hv; acc[1] += pa.y * hv; acc[2] += pa.z * hv; acc[3] += pa.w * hv;
      acc[4] += pb.x * hv; acc[5] += pb.y * hv; acc[6] += pb.z * hv; acc[7] += pb.w * hv;
    }
    __syncthreads();  // before next K^T overwrite
  }
#pragma unroll
  for (int q = 0; q < 8; ++q)
    ctx16[((size_t)(b * TT + i0 + q)) * HH + hd * HDIM + lane] = (half_t)(acc[q] / l[q]);
}

// ---------------- mean pool over T ----------------
__global__ void mean_pool(const float* __restrict__ x, float* __restrict__ out) {
  int b = blockIdx.x, j = threadIdx.x;
  const float* p = x + (size_t)b * TT * HH + j;
  float s = 0.f;
  for (int t = 0; t < TT; ++t) s += p[(size_t)t * HH];
  out[b * HH + j] = s * (1.f / 512.f);
}

// ---------------- FC layers ----------------
__global__ void fc1_k(const float* __restrict__ pooled, const float* __restrict__ w,
                      const float* __restrict__ bias, float* __restrict__ hid) {
  int b = blockIdx.x, o = threadIdx.x;  // 128 threads
  const float* pp = pooled + b * HH;
  const float* wp = w + o * HH;
  float s = 0.f;
#pragma unroll 4
  for (int k = 0; k < HH; ++k) s += pp[k] * wp[k];
  hid[b * 128 + o] = fmaxf(s + bias[o], 0.f);
}

__global__ void fc2_k(const float* __restrict__ hid, const float* __restrict__ w,
                      const float* __restrict__ bias, float* __restrict__ out) {
  int t = threadIdx.x;  // 256 = 32 m x 8 c
  int mm = t >> 3, c = t & 7;
  const float* hp = hid + mm * 128;
  const float* wp = w + c * 128;
  float s = 0.f;
#pragma unroll 4
  for (int k = 0; k < 128; ++k) s += hp[k] * wp[k];
  out[mm * 8 + c] = s + bias[c];
}

extern "C" void kernel_launch(void* const* d_in, const int* in_sizes, int n_in,
                              void* d_out, int out_size, void* d_ws, size_t ws_size,
                              hipStream_t stream) {
  (void)in_sizes; (void)n_in; (void)out_size; (void)ws_size;
  const float* x    = (const float*)d_in[0];
  const float* Wih0 = (const float*)d_in[1];
  const float* Whh0 = (const float*)d_in[2];
  const float* bih0 = (const float*)d_in[3];
  const float* bhh0 = (const float*)d_in[4];
  const float* Wih1 = (const float*)d_in[5];
  const float* Whh1 = (const float*)d_in[6];
  const float* bih1 = (const float*)d_in[7];
  const float* bhh1 = (const float*)d_in[8];
  const float* gatW = (const float*)d_in[9];
  const float* gatA = (const float*)d_in[10];
  const float* lng  = (const float*)d_in[11];
  const float* lnb  = (const float*)d_in[12];
  const float* inw  = (const float*)d_in[13];
  const float* inb  = (const float*)d_in[14];
  const float* outw = (const float*)d_in[15];
  const float* outb = (const float*)d_in[16];
  const float* f1w  = (const float*)d_in[17];
  const float* f1b  = (const float*)d_in[18];
  const float* f2w  = (const float*)d_in[19];
  const float* f2b  = (const float*)d_in[20];
  float* out = (float*)d_out;
  float* ws = (float*)d_ws;

  // fp32 regions:
  float* XPA   = ws;                  // 16384*768: xp0 -> xp1 -> qkv
  float* G0    = ws + 12582912;       // gat_out (gru0 fp32 h never stored)
  float* G1    = G0 + 4194304;        // gru1-out (fp32, for ln_res)
  float* Yb    = G1 + 4194304;        // [f16 G0_16 | f16 G1_16] -> attn_out fp32
  float* HGAT  = Yb + 4194304;        // gat feats fp32 -> [f16 CTX16 | f16 Y16]
  float* GATWTf= HGAT + 4194304;
  float* FSRC  = GATWTf + 65536;
  float* FDST  = FSRC + 65536;
  float* POOL  = FDST + 65536;
  float* HIDb  = POOL + 8192;
  float* W16b  = HIDb + 4096;         // f16 weight pool (~1.1 MB)

  // f16 aliases (lifetimes verified against launch order):
  half_t* X16     = (half_t*)G1;                   // dead before gru1 writes G1
  half_t* G0_16   = (half_t*)Yb;                   // dead before attn_out write
  half_t* G1_16   = (half_t*)(Yb + 2097152);
  half_t* CTX16   = (half_t*)HGAT;                 // written after gat phase done
  half_t* Y16     = (half_t*)(HGAT + 2097152);
  half_t* GATWT16 = (half_t*)GATWTf;
  half_t* W16ih0  = (half_t*)W16b;
  half_t* W16ih1  = (half_t*)(W16b + 49152);
  half_t* W16in   = (half_t*)(W16b + 49152 + 98304);
  half_t* W16out  = (half_t*)(W16b + 49152 + 98304 + 98304);

  // 0. casts (weights once; x once)
  castk<<<2048, 256, 0, stream>>>(x, X16, 2097152);
  castk<<<96, 256, 0, stream>>>(Wih0, W16ih0, 98304);
  castk<<<192, 256, 0, stream>>>(Wih1, W16ih1, 196608);
  castk<<<192, 256, 0, stream>>>(inw, W16in, 196608);
  castk<<<64, 256, 0, stream>>>(outw, W16out, 65536);
  gat_wt<<<256, 256, 0, stream>>>(gatW, GATWT16);
  // 1. xp0 = x @ W_ih0^T + b_ih0   (MFMA f16)
  gemm_f16<<<dim3(12, 128), 256, 0, stream>>>(X16, W16ih0, bih0, XPA, 16384, 768, 128);
  // 2. GRU layer 0 (fp32 h not needed -> nullptr)
  gru_layer<<<32, 512, 0, stream>>>(XPA, Whh0, bhh0, nullptr, G0_16);
  // 3. xp1 = g0 @ W_ih1^T + b_ih1
  gemm_f16<<<dim3(12, 128), 256, 0, stream>>>(G0_16, W16ih1, bih1, XPA, 16384, 768, 256);
  // 4. GRU layer 1
  gru_layer<<<32, 512, 0, stream>>>(XPA, Whh1, bhh1, G1, G1_16);
  // 5. GAT per-head features + attention
  gemm_f16<<<dim3(4, 128), 256, 0, stream>>>(G1_16, GATWT16, nullptr, HGAT, 16384, 256, 256);
  gat_fsd<<<dim3(32, 4), 512, 0, stream>>>(HGAT, gatA, FSRC, FDST);
  gat_attn<<<dim3(16, 4, 32), 256, 0, stream>>>(HGAT, FSRC, FDST, G0);
  // 6. y = LN(g + gat_out) -> f16
  ln_res<<<4096, 256, 0, stream>>>(G1, G0, lng, lnb, Y16);
  // 7. MHA
  gemm_f16<<<dim3(12, 128), 256, 0, stream>>>(Y16, W16in, inb, XPA, 16384, 768, 256);
  mha_attn<<<dim3(16, 4, 32), 256, 0, stream>>>(XPA, CTX16);
  gemm_f16<<<dim3(4, 128), 256, 0, stream>>>(CTX16, W16out, outb, Yb, 16384, 256, 256);
  // 8. pool + FC head
  mean_pool<<<32, 256, 0, stream>>>(Yb, POOL);
  fc1_k<<<32, 128, 0, stream>>>(POOL, f1w, f1b, HIDb);
  fc2_k<<<1, 256, 0, stream>>>(HIDb, f2w, f2b, out);
}

// Round 5
// 1678.145 us; speedup vs baseline: 1.4510x; 1.1875x over previous
//
#include <hip/hip_runtime.h>
#include <math.h>

// Problem constants
#define BB 32
#define TT 512
#define INF_ 128
#define HH 256
#define H3 768
#define NHEADS 4
#define HDIM 64

typedef _Float16 half_t;
typedef half_t half2_t __attribute__((ext_vector_type(2)));
typedef half_t half4_t __attribute__((ext_vector_type(4)));
typedef half_t f16x8 __attribute__((ext_vector_type(8)));
typedef float f32x4 __attribute__((ext_vector_type(4)));

#if defined(__has_builtin)
#if __has_builtin(__builtin_amdgcn_fdot2)
#define FDOT2(a, b, c) __builtin_amdgcn_fdot2((a), (b), (c), false)
#endif
#endif
#ifndef FDOT2
#define FDOT2(a, b, c) fmaf((float)(a).x, (float)(b).x, fmaf((float)(a).y, (float)(b).y, (c)))
#endif

#define BCH(x) __builtin_bit_cast(half2_t, x)
#define PKH(a, b) __builtin_bit_cast(unsigned, half2_t{(half_t)(a), (half_t)(b)})

// ---------------- wave helpers (wave = 64 on CDNA) ----------------
__device__ __forceinline__ float wsum(float v) {
#pragma unroll
  for (int o = 32; o > 0; o >>= 1) v += __shfl_xor(v, o, 64);
  return v;
}
__device__ __forceinline__ float wmax(float v) {
#pragma unroll
  for (int o = 32; o > 0; o >>= 1) v = fmaxf(v, __shfl_xor(v, o, 64));
  return v;
}

// ---------------- fp32 -> f16 cast (n % 1024 == 0) ----------------
__global__ void castk(const float* __restrict__ s, half_t* __restrict__ d, int n) {
  int i = (blockIdx.x * 256 + threadIdx.x) * 4;
  if (i < n) {
    float4 v = *(const float4*)(s + i);
    half4_t o = {(half_t)v.x, (half_t)v.y, (half_t)v.z, (half_t)v.w};
    *(half4_t*)(d + i) = o;
  }
}

__device__ __forceinline__ f16x8 pk16(float4 a, float4 b) {
  return f16x8{(half_t)a.x, (half_t)a.y, (half_t)a.z, (half_t)a.w,
               (half_t)b.x, (half_t)b.y, (half_t)b.z, (half_t)b.w};
}

// ---------------- MFMA f16 GEMM: C[M,N] = A[M,K] * B[N,K]^T + bias -------
__global__ __launch_bounds__(256) void gemm_f16(
    const half_t* __restrict__ A, const half_t* __restrict__ B,
    const float* __restrict__ bias, float* __restrict__ C,
    int M, int N, int K) {
  __shared__ __align__(16) half_t As[128][40];
  __shared__ __align__(16) half_t Bs[64][40];
  const int tid = threadIdx.x;
  const int wave = tid >> 6, lane = tid & 63;
  const int m0 = blockIdx.y * 128, n0 = blockIdx.x * 64;
  const int mrow = lane & 15, quad = lane >> 4;
  f32x4 acc00 = {0.f, 0.f, 0.f, 0.f}, acc01 = acc00, acc02 = acc00, acc03 = acc00;
  f32x4 acc10 = acc00, acc11 = acc00, acc12 = acc00, acc13 = acc00;
  for (int k0 = 0; k0 < K; k0 += 32) {
    __syncthreads();  // previous iter's fragments consumed
#pragma unroll
    for (int u = 0; u < 2; ++u) {  // stage A: 128 rows x 32 halfs
      int idx = tid + u * 256;
      int row = idx >> 2, seg = idx & 3;
      *(f16x8*)&As[row][seg * 8] =
          *(const f16x8*)&A[(size_t)(m0 + row) * K + k0 + seg * 8];
    }
    {  // stage B: 64 rows x 32 halfs
      int row = tid >> 2, seg = tid & 3;
      *(f16x8*)&Bs[row][seg * 8] =
          *(const f16x8*)&B[(size_t)(n0 + row) * K + k0 + seg * 8];
    }
    __syncthreads();
    f16x8 af0 = *(const f16x8*)&As[wave * 32 + mrow][quad * 8];
    f16x8 af1 = *(const f16x8*)&As[wave * 32 + 16 + mrow][quad * 8];
    f16x8 bf0 = *(const f16x8*)&Bs[mrow][quad * 8];
    f16x8 bf1 = *(const f16x8*)&Bs[16 + mrow][quad * 8];
    f16x8 bf2 = *(const f16x8*)&Bs[32 + mrow][quad * 8];
    f16x8 bf3 = *(const f16x8*)&Bs[48 + mrow][quad * 8];
    acc00 = __builtin_amdgcn_mfma_f32_16x16x32_f16(af0, bf0, acc00, 0, 0, 0);
    acc01 = __builtin_amdgcn_mfma_f32_16x16x32_f16(af0, bf1, acc01, 0, 0, 0);
    acc02 = __builtin_amdgcn_mfma_f32_16x16x32_f16(af0, bf2, acc02, 0, 0, 0);
    acc03 = __builtin_amdgcn_mfma_f32_16x16x32_f16(af0, bf3, acc03, 0, 0, 0);
    acc10 = __builtin_amdgcn_mfma_f32_16x16x32_f16(af1, bf0, acc10, 0, 0, 0);
    acc11 = __builtin_amdgcn_mfma_f32_16x16x32_f16(af1, bf1, acc11, 0, 0, 0);
    acc12 = __builtin_amdgcn_mfma_f32_16x16x32_f16(af1, bf2, acc12, 0, 0, 0);
    acc13 = __builtin_amdgcn_mfma_f32_16x16x32_f16(af1, bf3, acc13, 0, 0, 0);
  }
  float bv0 = bias ? bias[n0 + mrow] : 0.f;
  float bv1 = bias ? bias[n0 + 16 + mrow] : 0.f;
  float bv2 = bias ? bias[n0 + 32 + mrow] : 0.f;
  float bv3 = bias ? bias[n0 + 48 + mrow] : 0.f;
  const int rb = m0 + wave * 32 + quad * 4;
#pragma unroll
  for (int r = 0; r < 4; ++r) {
    float* c0 = C + (size_t)(rb + r) * N + n0;
    c0[mrow] = acc00[r] + bv0;
    c0[16 + mrow] = acc01[r] + bv1;
    c0[32 + mrow] = acc02[r] + bv2;
    c0[48 + mrow] = acc03[r] + bv3;
    float* c1 = C + (size_t)(rb + 16 + r) * N + n0;
    c1[mrow] = acc10[r] + bv0;
    c1[16 + mrow] = acc11[r] + bv1;
    c1[32 + mrow] = acc12[r] + bv2;
    c1[48 + mrow] = acc13[r] + bv3;
  }
}

// ---------------- GRU recurrence: R14-exact 3x128 structure ---------------
// Proven 693 us/layer (R0 baseline). R1-R4 MFMA-GEMV attempts (broadcast-A,
// weights in regs) all landed 734-936 us: 384 KB of per-block weights
// saturates the register file at any occupancy; allocator overflow shows as
// ~700 VALU insts/step (spill or AGPR copies), invisible in FETCH_SIZE
// (L2-resident). Reverted to the empirically best structure.
// Thread (j,kh): regs r,z chunks 0-13 + n chunk 0 = 116 half2; streamed 19
// b128 groups at WSq[g*512+tid] (stride-1, 0 conflicts); h packed-f16 in
// hs[2][2][144] (+32B pad, broadcast reads). One barrier/step.
#define LDW(g, p, a, b, i)                             \
  {                                                    \
    float4 v = (p)[i];                                 \
    g##a = half2_t{(half_t)v.x, (half_t)v.y};          \
    g##b = half2_t{(half_t)v.z, (half_t)v.w};          \
  }
#define LDW28(g, p)                                                        \
  LDW(g, p, 0, 1, 0) LDW(g, p, 2, 3, 1) LDW(g, p, 4, 5, 2)                 \
  LDW(g, p, 6, 7, 3) LDW(g, p, 8, 9, 4) LDW(g, p, 10, 11, 5)               \
  LDW(g, p, 12, 13, 6) LDW(g, p, 14, 15, 7) LDW(g, p, 16, 17, 8)           \
  LDW(g, p, 18, 19, 9) LDW(g, p, 20, 21, 10) LDW(g, p, 22, 23, 11)         \
  LDW(g, p, 24, 25, 12) LDW(g, p, 26, 27, 13) LDW(g, p, 28, 29, 14)        \
  LDW(g, p, 30, 31, 15) LDW(g, p, 32, 33, 16) LDW(g, p, 34, 35, 17)        \
  LDW(g, p, 36, 37, 18) LDW(g, p, 38, 39, 19) LDW(g, p, 40, 41, 20)        \
  LDW(g, p, 42, 43, 21) LDW(g, p, 44, 45, 22) LDW(g, p, 46, 47, 23)        \
  LDW(g, p, 48, 49, 24) LDW(g, p, 50, 51, 25) LDW(g, p, 52, 53, 26)        \
  LDW(g, p, 54, 55, 27)

#define DECL56(g)                                                          \
  half2_t g##0, g##1, g##2, g##3, g##4, g##5, g##6, g##7, g##8, g##9,      \
      g##10, g##11, g##12, g##13, g##14, g##15, g##16, g##17, g##18,       \
      g##19, g##20, g##21, g##22, g##23, g##24, g##25, g##26, g##27,       \
      g##28, g##29, g##30, g##31, g##32, g##33, g##34, g##35, g##36,       \
      g##37, g##38, g##39, g##40, g##41, g##42, g##43, g##44, g##45,       \
      g##46, g##47, g##48, g##49, g##50, g##51, g##52, g##53, g##54, g##55;

// chunks 1..13: r,z from regs, n from one b128 group (group c8-1)
#define CHA(c8, a0, a1, a2, a3)                                            \
  {                                                                        \
    float4 v = hp4[c8];                                                    \
    uint4 nv = WSq[((c8)-1) * 512 + tid];                                  \
    half2_t t0 = __builtin_bit_cast(half2_t, v.x);                         \
    half2_t t1 = __builtin_bit_cast(half2_t, v.y);                         \
    half2_t t2 = __builtin_bit_cast(half2_t, v.z);                         \
    half2_t t3 = __builtin_bit_cast(half2_t, v.w);                         \
    ar = FDOT2(wr##a0, t0, ar); az = FDOT2(wz##a0, t0, az); an = FDOT2(BCH(nv.x), t0, an); \
    ar = FDOT2(wr##a1, t1, ar); az = FDOT2(wz##a1, t1, az); an = FDOT2(BCH(nv.y), t1, an); \
    ar = FDOT2(wr##a2, t2, ar); az = FDOT2(wz##a2, t2, az); an = FDOT2(BCH(nv.z), t2, an); \
    ar = FDOT2(wr##a3, t3, ar); az = FDOT2(wz##a3, t3, az); an = FDOT2(BCH(nv.w), t3, an); \
  }

// chunks 14,15: r,z,n all from LDS b128 groups
#define CHB(c8)                                                            \
  {                                                                        \
    float4 v = hp4[c8];                                                    \
    uint4 nv = WSq[((c8)-1) * 512 + tid];                                  \
    uint4 rv = WSq[(15 + ((c8)-14)) * 512 + tid];                          \
    uint4 zv = WSq[(17 + ((c8)-14)) * 512 + tid];                          \
    half2_t t0 = __builtin_bit_cast(half2_t, v.x);                         \
    half2_t t1 = __builtin_bit_cast(half2_t, v.y);                         \
    half2_t t2 = __builtin_bit_cast(half2_t, v.z);                         \
    half2_t t3 = __builtin_bit_cast(half2_t, v.w);                         \
    ar = FDOT2(BCH(rv.x), t0, ar); az = FDOT2(BCH(zv.x), t0, az); an = FDOT2(BCH(nv.x), t0, an); \
    ar = FDOT2(BCH(rv.y), t1, ar); az = FDOT2(BCH(zv.y), t1, az); an = FDOT2(BCH(nv.y), t1, an); \
    ar = FDOT2(BCH(rv.z), t2, ar); az = FDOT2(BCH(zv.z), t2, az); an = FDOT2(BCH(nv.z), t2, an); \
    ar = FDOT2(BCH(rv.w), t3, ar); az = FDOT2(BCH(zv.w), t3, az); an = FDOT2(BCH(nv.w), t3, an); \
  }

__device__ __forceinline__ uint4 pk8(const float* p) {
  float4 a = *(const float4*)p;
  float4 b = *(const float4*)(p + 4);
  return uint4{PKH(a.x, a.y), PKH(a.z, a.w), PKH(b.x, b.y), PKH(b.z, b.w)};
}

__global__ __launch_bounds__(512) void gru_layer(
    const float* __restrict__ xp, const float* __restrict__ Whh,
    const float* __restrict__ bhh, float* __restrict__ out,
    half_t* __restrict__ out16) {
  __shared__ __align__(16) uint4 WSq[19 * 512];    // 152 KB streamed weights
  __shared__ __align__(16) half_t hs[2][2][144];
  const int tid = threadIdx.x;
  const int kh = tid & 1, j = tid >> 1;
  const int b = blockIdx.x;
  const bool wf32 = (out != nullptr);  // uniform: layer 0 skips fp32 h-store
  DECL56(wr)
  DECL56(wz)
  half2_t wn0, wn1, wn2, wn3;
  {
    const float4* pr = (const float4*)(Whh + (size_t)j * HH + kh * 128);
    const float4* pz = (const float4*)(Whh + (size_t)(HH + j) * HH + kh * 128);
    const float4* pn = (const float4*)(Whh + (size_t)(2 * HH + j) * HH + kh * 128);
    LDW28(wr, pr)
    LDW28(wz, pz)
    LDW(wn, pn, 0, 1, 0)
    LDW(wn, pn, 2, 3, 1)
  }
  // Stage streamed weights: 19 b128 groups of 4 slots each per thread.
  {
    const float* rowN = Whh + (size_t)(2 * HH + j) * HH + kh * 128;
    const float* rowR = Whh + (size_t)j * HH + kh * 128;
    const float* rowZ = Whh + (size_t)(HH + j) * HH + kh * 128;
#pragma unroll
    for (int sg = 0; sg < 15; ++sg) WSq[sg * 512 + tid] = pk8(rowN + 8 + 8 * sg);
#pragma unroll
    for (int sg = 0; sg < 2; ++sg) WSq[(15 + sg) * 512 + tid] = pk8(rowR + 112 + 8 * sg);
#pragma unroll
    for (int sg = 0; sg < 2; ++sg) WSq[(17 + sg) * 512 + tid] = pk8(rowZ + 112 + 8 * sg);
  }
  const float br = bhh[j], bz = bhh[HH + j], bn = bhh[2 * HH + j];
  for (int i = tid; i < 288; i += 512) ((unsigned*)hs)[i] = 0u;
  __syncthreads();
  float hprev = 0.f;
  const float* xrow = xp + (size_t)b * TT * H3;
  float* orow = out + (size_t)b * TT * HH;
  half_t* orow16 = out16 + (size_t)b * TT * HH;
  for (int t = 0; t < TT; ++t) {
    float xr = xrow[j], xz = xrow[HH + j], xn = xrow[2 * HH + j];
    const float4* hp4 = (const float4*)&hs[t & 1][kh][0];
    float ar = 0.f, az = 0.f, an = 0.f;
    {  // chunk 0: r,z,n all regs
      float4 v = hp4[0];
      half2_t t0 = __builtin_bit_cast(half2_t, v.x);
      half2_t t1 = __builtin_bit_cast(half2_t, v.y);
      half2_t t2 = __builtin_bit_cast(half2_t, v.z);
      half2_t t3 = __builtin_bit_cast(half2_t, v.w);
      ar = FDOT2(wr0, t0, ar); az = FDOT2(wz0, t0, az); an = FDOT2(wn0, t0, an);
      ar = FDOT2(wr1, t1, ar); az = FDOT2(wz1, t1, az); an = FDOT2(wn1, t1, an);
      ar = FDOT2(wr2, t2, ar); az = FDOT2(wz2, t2, az); an = FDOT2(wn2, t2, an);
      ar = FDOT2(wr3, t3, ar); az = FDOT2(wz3, t3, az); an = FDOT2(wn3, t3, an);
    }
    CHA(1, 4, 5, 6, 7)
    CHA(2, 8, 9, 10, 11)
    CHA(3, 12, 13, 14, 15)
    CHA(4, 16, 17, 18, 19)
    CHA(5, 20, 21, 22, 23)
    CHA(6, 24, 25, 26, 27)
    CHA(7, 28, 29, 30, 31)
    CHA(8, 32, 33, 34, 35)
    CHA(9, 36, 37, 38, 39)
    CHA(10, 40, 41, 42, 43)
    CHA(11, 44, 45, 46, 47)
    CHA(12, 48, 49, 50, 51)
    CHA(13, 52, 53, 54, 55)
    CHB(14)
    CHB(15)
    ar += __shfl_xor(ar, 1);
    az += __shfl_xor(az, 1);
    an += __shfl_xor(an, 1);
    float rg = 1.f / (1.f + __expf(-(xr + ar + br)));
    float zg = 1.f / (1.f + __expf(-(xz + az + bz)));
    float ng = 2.f / (1.f + __expf(-2.f * (xn + rg * (an + bn)))) - 1.f;  // tanh, inf-safe
    float hnew = (1.f - zg) * ng + zg * hprev;
    hprev = hnew;
    float hpart = __shfl_xor(hnew, 2);  // lane (kh=0, even j) gets h_{j+1}
    if ((tid & 3) == 0) {               // kh==0 && j even: one b32 packed write
      half2_t pk;
      pk.x = (half_t)hnew;
      pk.y = (half_t)hpart;
      *(half2_t*)&hs[(t + 1) & 1][j >> 7][j & 127] = pk;
    }
    if (kh == 0) {
      orow16[j] = (half_t)hnew;
      if (wf32) orow[j] = hnew;
    }
    __syncthreads();
    xrow += H3;
    orow += HH;
    orow16 += HH;
  }
}

// ---------------- gat_W transpose -> f16: [4,256,64] -> [256 cols][256 k] --
__global__ void gat_wt(const float* __restrict__ W, half_t* __restrict__ Wt) {
  int idx = blockIdx.x * 256 + threadIdx.x;  // [0, 65536)
  int col = idx >> 8, k = idx & 255;
  Wt[idx] = (half_t)W[((size_t)((col >> 6) * HH + k)) * HDIM + (col & 63)];
}

// ---------------- GAT f_src/f_dst ----------------
__global__ void gat_fsd(const float* __restrict__ hgat, const float* __restrict__ a,
                        float* __restrict__ fsrc, float* __restrict__ fdst) {
  int b = blockIdx.x, hd = blockIdx.y, t = threadIdx.x;  // block 512
  const float* hp = hgat + ((size_t)(b * TT + t)) * HH + hd * HDIM;
  const float* ap = a + hd * 2 * HDIM;
  float fs = 0.f, fd = 0.f;
#pragma unroll 4
  for (int d = 0; d < HDIM; ++d) {
    float hv = hp[d];
    fs += hv * ap[d];
    fd += hv * ap[HDIM + d];
  }
  fsrc[(b * NHEADS + hd) * TT + t] = fs;
  fdst[(b * NHEADS + hd) * TT + t] = fd;
}

// ---------------- GAT flash attention (MFMA PV) ---------------------------
// Block = 64 q rows (grid 8 x 4 hd x 32 b), 4 waves x 16 q. Scores are
// rank-1 (fi + fd[j]) -> softmax on VALU, lane owns q=lane&15, j-range
// quad*32..+32. P stored f16 in LDS [q][j]; PV = P[16,128] @ H^T[64,128]^T
// on the matrix pipe using the gemm_f16 fragment conventions (A-frag
// [m=lane&15][k=(lane>>4)*8+i], C row=(lane>>4)*4+r col=lane&15).
__global__ __launch_bounds__(256) void gat_attn(
    const float* __restrict__ hgat, const float* __restrict__ fsrc,
    const float* __restrict__ fdst, float* __restrict__ out) {
  __shared__ __align__(16) half_t Htt[64][136];     // H^T per j-tile
  __shared__ __align__(16) half_t Ps[4][16][136];   // per-wave P (f16)
  __shared__ __align__(16) float fd[128];
  const int tid = threadIdx.x, wave = tid >> 6, lane = tid & 63;
  const int mrow = lane & 15, quad = lane >> 4;
  const int hd = blockIdx.y, b = blockIdx.z;
  const int q0 = blockIdx.x * 64;
  const float fi = fsrc[(size_t)(b * NHEADS + hd) * TT + q0 + wave * 16 + mrow];
  const float* fdp = fdst + (size_t)(b * NHEADS + hd) * TT;
  float m = -1e30f, l = 0.f;
  f32x4 o[4];
#pragma unroll
  for (int n = 0; n < 4; ++n) o[n] = f32x4{0.f, 0.f, 0.f, 0.f};
  for (int jt = 0; jt < TT; jt += 128) {
#pragma unroll
    for (int u = 0; u < 4; ++u) {  // stage H^T: Htt[d][j] (f16)
      int idx = tid + u * 256;
      int j = idx >> 3, s = (idx & 7) * 8;
      const float* hp = hgat + (size_t)(b * TT + jt + j) * HH + hd * HDIM + s;
      float4 ha = *(const float4*)hp, hb = *(const float4*)(hp + 4);
      Htt[s + 0][j] = (half_t)ha.x; Htt[s + 1][j] = (half_t)ha.y;
      Htt[s + 2][j] = (half_t)ha.z; Htt[s + 3][j] = (half_t)ha.w;
      Htt[s + 4][j] = (half_t)hb.x; Htt[s + 5][j] = (half_t)hb.y;
      Htt[s + 6][j] = (half_t)hb.z; Htt[s + 7][j] = (half_t)hb.w;
    }
    if (tid < 32) *(float4*)&fd[tid * 4] = *(const float4*)&fdp[jt + tid * 4];
    __syncthreads();
    float p[32];
    float mx = -1e30f;
#pragma unroll
    for (int g = 0; g < 8; ++g) {
      float4 f4 = *(const float4*)&fd[quad * 32 + g * 4];
      float e0 = fi + f4.x; e0 = (e0 > 0.f) ? e0 : 0.2f * e0;
      float e1 = fi + f4.y; e1 = (e1 > 0.f) ? e1 : 0.2f * e1;
      float e2 = fi + f4.z; e2 = (e2 > 0.f) ? e2 : 0.2f * e2;
      float e3 = fi + f4.w; e3 = (e3 > 0.f) ? e3 : 0.2f * e3;
      p[g * 4 + 0] = e0; p[g * 4 + 1] = e1; p[g * 4 + 2] = e2; p[g * 4 + 3] = e3;
      mx = fmaxf(mx, fmaxf(fmaxf(e0, e1), fmaxf(e2, e3)));
    }
    mx = fmaxf(mx, __shfl_xor(mx, 16, 64));  // reduce over the 4 j-groups
    mx = fmaxf(mx, __shfl_xor(mx, 32, 64));
    float mn = fmaxf(m, mx);
    float corr = __expf(m - mn);
    m = mn;
    float ls = 0.f;
#pragma unroll
    for (int i = 0; i < 32; ++i) { p[i] = __expf(p[i] - mn); ls += p[i]; }
    ls += __shfl_xor(ls, 16, 64);
    ls += __shfl_xor(ls, 32, 64);
    l = l * corr + ls;
    float cr[4];  // corr for PV acc rows q' = quad*4+r (held by lane q')
#pragma unroll
    for (int r = 0; r < 4; ++r) cr[r] = __shfl(corr, quad * 4 + r, 64);
#pragma unroll
    for (int n = 0; n < 4; ++n) {
      o[n][0] *= cr[0]; o[n][1] *= cr[1]; o[n][2] *= cr[2]; o[n][3] *= cr[3];
    }
#pragma unroll
    for (int s8 = 0; s8 < 4; ++s8) {  // P f16 -> LDS [q][j]
      f16x8 pkv = {(half_t)p[s8 * 8 + 0], (half_t)p[s8 * 8 + 1],
                   (half_t)p[s8 * 8 + 2], (half_t)p[s8 * 8 + 3],
                   (half_t)p[s8 * 8 + 4], (half_t)p[s8 * 8 + 5],
                   (half_t)p[s8 * 8 + 6], (half_t)p[s8 * 8 + 7]};
      *(f16x8*)&Ps[wave][mrow][quad * 32 + s8 * 8] = pkv;
    }
    __syncthreads();
    f16x8 pa0 = *(const f16x8*)&Ps[wave][mrow][0 * 32 + quad * 8];
    f16x8 pa1 = *(const f16x8*)&Ps[wave][mrow][1 * 32 + quad * 8];
    f16x8 pa2 = *(const f16x8*)&Ps[wave][mrow][2 * 32 + quad * 8];
    f16x8 pa3 = *(const f16x8*)&Ps[wave][mrow][3 * 32 + quad * 8];
#pragma unroll
    for (int n = 0; n < 4; ++n) {
      f16x8 vb0 = *(const f16x8*)&Htt[n * 16 + mrow][0 * 32 + quad * 8];
      f16x8 vb1 = *(const f16x8*)&Htt[n * 16 + mrow][1 * 32 + quad * 8];
      f16x8 vb2 = *(const f16x8*)&Htt[n * 16 + mrow][2 * 32 + quad * 8];
      f16x8 vb3 = *(const f16x8*)&Htt[n * 16 + mrow][3 * 32 + quad * 8];
      o[n] = __builtin_amdgcn_mfma_f32_16x16x32_f16(pa0, vb0, o[n], 0, 0, 0);
      o[n] = __builtin_amdgcn_mfma_f32_16x16x32_f16(pa1, vb1, o[n], 0, 0, 0);
      o[n] = __builtin_amdgcn_mfma_f32_16x16x32_f16(pa2, vb2, o[n], 0, 0, 0);
      o[n] = __builtin_amdgcn_mfma_f32_16x16x32_f16(pa3, vb3, o[n], 0, 0, 0);
    }
    __syncthreads();  // before next tile's staging overwrites Htt
  }
  float lr[4];
#pragma unroll
  for (int r = 0; r < 4; ++r) lr[r] = __shfl(l, quad * 4 + r, 64);
#pragma unroll
  for (int n = 0; n < 4; ++n)
#pragma unroll
    for (int r = 0; r < 4; ++r)
      out[(size_t)(b * TT + q0 + wave * 16 + quad * 4 + r) * HH + hd * HDIM +
          n * 16 + mrow] = o[n][r] / lr[r];
}

// ---------------- residual + LayerNorm (f16 output for MFMA GEMM) ---------
__global__ __launch_bounds__(256) void ln_res(
    const float* __restrict__ g, const float* __restrict__ gat,
    const float* __restrict__ gamma, const float* __restrict__ beta,
    half_t* __restrict__ y16) {
  int wave = threadIdx.x >> 6, lane = threadIdx.x & 63;
  size_t n = (size_t)blockIdx.x * 4 + wave;
  float4 v = ((const float4*)(g + n * HH))[lane];
  float4 w = ((const float4*)(gat + n * HH))[lane];
  v.x += w.x; v.y += w.y; v.z += w.z; v.w += w.w;
  float mu = wsum(v.x + v.y + v.z + v.w) * (1.f / 256.f);
  float dx = v.x - mu, dy = v.y - mu, dz = v.z - mu, dw = v.w - mu;
  float var = wsum(dx * dx + dy * dy + dz * dz + dw * dw) * (1.f / 256.f);
  float rstd = rsqrtf(var + 1e-5f);
  float4 gm = ((const float4*)gamma)[lane];
  float4 bt = ((const float4*)beta)[lane];
  half4_t o = {(half_t)(dx * rstd * gm.x + bt.x), (half_t)(dy * rstd * gm.y + bt.y),
               (half_t)(dz * rstd * gm.z + bt.z), (half_t)(dw * rstd * gm.w + bt.w)};
  ((half4_t*)(y16 + n * HH))[lane] = o;
}

// ---------------- MHA flash attention (MFMA QK + PV, f16 ctx output) ------
// Block = 64 q (grid 8 x 4 hd x 32 b), 4 waves x 16 q. QK^T and PV on the
// matrix pipe; online softmax on S in C-layout (row q=(lane>>4)*4+r, col
// j=n*16+(lane&15)), j-reduce = per-lane over 8 accs + shfl_xor 1,2,4,8.
__global__ __launch_bounds__(256) void mha_attn(const float* __restrict__ qkv,
                                                half_t* __restrict__ ctx16) {
  __shared__ __align__(16) half_t Qs[64][72];
  __shared__ __align__(16) half_t Ks[128][72];
  __shared__ __align__(16) half_t Vt[64][136];
  __shared__ __align__(16) half_t Ps[4][16][136];
  const int tid = threadIdx.x, wave = tid >> 6, lane = tid & 63;
  const int mrow = lane & 15, quad = lane >> 4;
  const int hd = blockIdx.y, b = blockIdx.z;
  const int q0 = blockIdx.x * 64;
  {  // stage Q: 64 q x 64 d -> f16
    int r = tid >> 2, s = (tid & 3) * 16;
    const float* src = qkv + (size_t)(b * TT + q0 + r) * H3 + hd * HDIM + s;
    float4 a = *(const float4*)src, b4 = *(const float4*)(src + 4);
    float4 c = *(const float4*)(src + 8), d4 = *(const float4*)(src + 12);
    *(f16x8*)&Qs[r][s] = pk16(a, b4);
    *(f16x8*)&Qs[r][s + 8] = pk16(c, d4);
  }
  __syncthreads();
  f16x8 qa0 = *(const f16x8*)&Qs[wave * 16 + mrow][quad * 8];
  f16x8 qa1 = *(const f16x8*)&Qs[wave * 16 + mrow][32 + quad * 8];
  float m[4] = {-1e30f, -1e30f, -1e30f, -1e30f};
  float l[4] = {0.f, 0.f, 0.f, 0.f};
  f32x4 o[4];
#pragma unroll
  for (int n = 0; n < 4; ++n) o[n] = f32x4{0.f, 0.f, 0.f, 0.f};
  for (int jt = 0; jt < TT; jt += 128) {
#pragma unroll
    for (int u = 0; u < 4; ++u) {  // stage K [j][d] and V^T [d][j]
      int idx = tid + u * 256;
      int j = idx >> 3, s = (idx & 7) * 8;
      const float* kp = qkv + (size_t)(b * TT + jt + j) * H3 + HH + hd * HDIM + s;
      float4 ka = *(const float4*)kp, kb = *(const float4*)(kp + 4);
      *(f16x8*)&Ks[j][s] = pk16(ka, kb);
      const float* vp = kp + HH;
      float4 va = *(const float4*)vp, vb = *(const float4*)(vp + 4);
      Vt[s + 0][j] = (half_t)va.x; Vt[s + 1][j] = (half_t)va.y;
      Vt[s + 2][j] = (half_t)va.z; Vt[s + 3][j] = (half_t)va.w;
      Vt[s + 4][j] = (half_t)vb.x; Vt[s + 5][j] = (half_t)vb.y;
      Vt[s + 6][j] = (half_t)vb.z; Vt[s + 7][j] = (half_t)vb.w;
    }
    __syncthreads();
    f32x4 sAcc[8];
#pragma unroll
    for (int n = 0; n < 8; ++n) sAcc[n] = f32x4{0.f, 0.f, 0.f, 0.f};
#pragma unroll
    for (int n = 0; n < 8; ++n) {
      f16x8 kb0 = *(const f16x8*)&Ks[n * 16 + mrow][quad * 8];
      f16x8 kb1 = *(const f16x8*)&Ks[n * 16 + mrow][32 + quad * 8];
      sAcc[n] = __builtin_amdgcn_mfma_f32_16x16x32_f16(qa0, kb0, sAcc[n], 0, 0, 0);
      sAcc[n] = __builtin_amdgcn_mfma_f32_16x16x32_f16(qa1, kb1, sAcc[n], 0, 0, 0);
    }
    float p[8][4];
    float mx[4] = {-1e30f, -1e30f, -1e30f, -1e30f};
#pragma unroll
    for (int n = 0; n < 8; ++n)
#pragma unroll
      for (int r = 0; r < 4; ++r) {
        float v = sAcc[n][r] * 0.125f;
        p[n][r] = v;
        mx[r] = fmaxf(mx[r], v);
      }
#pragma unroll
    for (int off = 8; off > 0; off >>= 1)
#pragma unroll
      for (int r = 0; r < 4; ++r) mx[r] = fmaxf(mx[r], __shfl_xor(mx[r], off, 64));
    float corr[4], ls[4];
#pragma unroll
    for (int r = 0; r < 4; ++r) {
      float mn = fmaxf(m[r], mx[r]);
      corr[r] = __expf(m[r] - mn);
      m[r] = mn;
      ls[r] = 0.f;
    }
#pragma unroll
    for (int n = 0; n < 8; ++n)
#pragma unroll
      for (int r = 0; r < 4; ++r) {
        float e = __expf(p[n][r] - m[r]);
        p[n][r] = e;
        ls[r] += e;
      }
#pragma unroll
    for (int off = 8; off > 0; off >>= 1)
#pragma unroll
      for (int r = 0; r < 4; ++r) ls[r] += __shfl_xor(ls[r], off, 64);
#pragma unroll
    for (int r = 0; r < 4; ++r) l[r] = l[r] * corr[r] + ls[r];
#pragma unroll
    for (int n = 0; n < 4; ++n) {
      o[n][0] *= corr[0]; o[n][1] *= corr[1]; o[n][2] *= corr[2]; o[n][3] *= corr[3];
    }
#pragma unroll
    for (int n = 0; n < 8; ++n)
#pragma unroll
      for (int r = 0; r < 4; ++r)
        Ps[wave][quad * 4 + r][n * 16 + mrow] = (half_t)p[n][r];
    __syncthreads();
    f16x8 pa0 = *(const f16x8*)&Ps[wave][mrow][0 * 32 + quad * 8];
    f16x8 pa1 = *(const f16x8*)&Ps[wave][mrow][1 * 32 + quad * 8];
    f16x8 pa2 = *(const f16x8*)&Ps[wave][mrow][2 * 32 + quad * 8];
    f16x8 pa3 = *(const f16x8*)&Ps[wave][mrow][3 * 32 + quad * 8];
#pragma unroll
    for (int n = 0; n < 4; ++n) {
      f16x8 vb0 = *(const f16x8*)&Vt[n * 16 + mrow][0 * 32 + quad * 8];
      f16x8 vb1 = *(const f16x8*)&Vt[n * 16 + mrow][1 * 32 + quad * 8];
      f16x8 vb2 = *(const f16x8*)&Vt[n * 16 + mrow][2 * 32 + quad * 8];
      f16x8 vb3 = *(const f16x8*)&Vt[n * 16 + mrow][3 * 32 + quad * 8];
      o[n] = __builtin_amdgcn_mfma_f32_16x16x32_f16(pa0, vb0, o[n], 0, 0, 0);
      o[n] = __builtin_amdgcn_mfma_f32_16x16x32_f16(pa1, vb1, o[n], 0, 0, 0);
      o[n] = __builtin_amdgcn_mfma_f32_16x16x32_f16(pa2, vb2, o[n], 0, 0, 0);
      o[n] = __builtin_amdgcn_mfma_f32_16x16x32_f16(pa3, vb3, o[n], 0, 0, 0);
    }
    __syncthreads();  // before next tile's staging overwrites Ks/Vt
  }
#pragma unroll
  for (int n = 0; n < 4; ++n)
#pragma unroll
    for (int r = 0; r < 4; ++r)
      ctx16[(size_t)(b * TT + q0 + wave * 16 + quad * 4 + r) * HH + hd * HDIM +
            n * 16 + mrow] = (half_t)(o[n][r] / l[r]);
}

// ---------------- mean pool over T ----------------
__global__ void mean_pool(const float* __restrict__ x, float* __restrict__ out) {
  int b = blockIdx.x, j = threadIdx.x;
  const float* p = x + (size_t)b * TT * HH + j;
  float s = 0.f;
  for (int t = 0; t < TT; ++t) s += p[(size_t)t * HH];
  out[b * HH + j] = s * (1.f / 512.f);
}

// ---------------- FC layers ----------------
__global__ void fc1_k(const float* __restrict__ pooled, const float* __restrict__ w,
                      const float* __restrict__ bias, float* __restrict__ hid) {
  int b = blockIdx.x, o = threadIdx.x;  // 128 threads
  const float* pp = pooled + b * HH;
  const float* wp = w + o * HH;
  float s = 0.f;
#pragma unroll 4
  for (int k = 0; k < HH; ++k) s += pp[k] * wp[k];
  hid[b * 128 + o] = fmaxf(s + bias[o], 0.f);
}

__global__ void fc2_k(const float* __restrict__ hid, const float* __restrict__ w,
                      const float* __restrict__ bias, float* __restrict__ out) {
  int t = threadIdx.x;  // 256 = 32 m x 8 c
  int mm = t >> 3, c = t & 7;
  const float* hp = hid + mm * 128;
  const float* wp = w + c * 128;
  float s = 0.f;
#pragma unroll 4
  for (int k = 0; k < 128; ++k) s += hp[k] * wp[k];
  out[mm * 8 + c] = s + bias[c];
}

extern "C" void kernel_launch(void* const* d_in, const int* in_sizes, int n_in,
                              void* d_out, int out_size, void* d_ws, size_t ws_size,
                              hipStream_t stream) {
  (void)in_sizes; (void)n_in; (void)out_size; (void)ws_size;
  const float* x    = (const float*)d_in[0];
  const float* Wih0 = (const float*)d_in[1];
  const float* Whh0 = (const float*)d_in[2];
  const float* bih0 = (const float*)d_in[3];
  const float* bhh0 = (const float*)d_in[4];
  const float* Wih1 = (const float*)d_in[5];
  const float* Whh1 = (const float*)d_in[6];
  const float* bih1 = (const float*)d_in[7];
  const float* bhh1 = (const float*)d_in[8];
  const float* gatW = (const float*)d_in[9];
  const float* gatA = (const float*)d_in[10];
  const float* lng  = (const float*)d_in[11];
  const float* lnb  = (const float*)d_in[12];
  const float* inw  = (const float*)d_in[13];
  const float* inb  = (const float*)d_in[14];
  const float* outw = (const float*)d_in[15];
  const float* outb = (const float*)d_in[16];
  const float* f1w  = (const float*)d_in[17];
  const float* f1b  = (const float*)d_in[18];
  const float* f2w  = (const float*)d_in[19];
  const float* f2b  = (const float*)d_in[20];
  float* out = (float*)d_out;
  float* ws = (float*)d_ws;

  // fp32 regions:
  float* XPA   = ws;                  // 16384*768: xp0 -> xp1 -> qkv
  float* G0    = ws + 12582912;       // gat_out (gru0 fp32 h never stored)
  float* G1    = G0 + 4194304;        // gru1-out (fp32, for ln_res)
  float* Yb    = G1 + 4194304;        // [f16 G0_16 | f16 G1_16] -> attn_out fp32
  float* HGAT  = Yb + 4194304;        // gat feats fp32 -> [f16 CTX16 | f16 Y16]
  float* GATWTf= HGAT + 4194304;
  float* FSRC  = GATWTf + 65536;
  float* FDST  = FSRC + 65536;
  float* POOL  = FDST + 65536;
  float* HIDb  = POOL + 8192;
  float* W16b  = HIDb + 4096;         // f16 weight pool (~1.1 MB)

  // f16 aliases (lifetimes verified against launch order):
  half_t* X16     = (half_t*)G1;                   // dead before gru1 writes G1
  half_t* G0_16   = (half_t*)Yb;                   // dead before attn_out write
  half_t* G1_16   = (half_t*)(Yb + 2097152);
  half_t* CTX16   = (half_t*)HGAT;                 // written after gat phase done
  half_t* Y16     = (half_t*)(HGAT + 2097152);
  half_t* GATWT16 = (half_t*)GATWTf;
  half_t* W16ih0  = (half_t*)W16b;
  half_t* W16ih1  = (half_t*)(W16b + 49152);
  half_t* W16in   = (half_t*)(W16b + 49152 + 98304);
  half_t* W16out  = (half_t*)(W16b + 49152 + 98304 + 98304);

  // 0. casts (weights once; x once)
  castk<<<2048, 256, 0, stream>>>(x, X16, 2097152);
  castk<<<96, 256, 0, stream>>>(Wih0, W16ih0, 98304);
  castk<<<192, 256, 0, stream>>>(Wih1, W16ih1, 196608);
  castk<<<192, 256, 0, stream>>>(inw, W16in, 196608);
  castk<<<64, 256, 0, stream>>>(outw, W16out, 65536);
  gat_wt<<<256, 256, 0, stream>>>(gatW, GATWT16);
  // 1. xp0 = x @ W_ih0^T + b_ih0   (MFMA f16)
  gemm_f16<<<dim3(12, 128), 256, 0, stream>>>(X16, W16ih0, bih0, XPA, 16384, 768, 128);
  // 2. GRU layer 0 (fp32 h not needed -> nullptr)
  gru_layer<<<32, 512, 0, stream>>>(XPA, Whh0, bhh0, nullptr, G0_16);
  // 3. xp1 = g0 @ W_ih1^T + b_ih1
  gemm_f16<<<dim3(12, 128), 256, 0, stream>>>(G0_16, W16ih1, bih1, XPA, 16384, 768, 256);
  // 4. GRU layer 1
  gru_layer<<<32, 512, 0, stream>>>(XPA, Whh1, bhh1, G1, G1_16);
  // 5. GAT per-head features + attention
  gemm_f16<<<dim3(4, 128), 256, 0, stream>>>(G1_16, GATWT16, nullptr, HGAT, 16384, 256, 256);
  gat_fsd<<<dim3(32, 4), 512, 0, stream>>>(HGAT, gatA, FSRC, FDST);
  gat_attn<<<dim3(8, 4, 32), 256, 0, stream>>>(HGAT, FSRC, FDST, G0);
  // 6. y = LN(g + gat_out) -> f16
  ln_res<<<4096, 256, 0, stream>>>(G1, G0, lng, lnb, Y16);
  // 7. MHA
  gemm_f16<<<dim3(12, 128), 256, 0, stream>>>(Y16, W16in, inb, XPA, 16384, 768, 256);
  mha_attn<<<dim3(8, 4, 32), 256, 0, stream>>>(XPA, CTX16);
  gemm_f16<<<dim3(4, 128), 256, 0, stream>>>(CTX16, W16out, outb, Yb, 16384, 256, 256);
  // 8. pool + FC head
  mean_pool<<<32, 256, 0, stream>>>(Yb, POOL);
  fc1_k<<<32, 128, 0, stream>>>(POOL, f1w, f1b, HIDb);
  fc2_k<<<1, 256, 0, stream>>>(HIDb, f2w, f2b, out);
}

// Round 6
// 1641.188 us; speedup vs baseline: 1.4836x; 1.0225x over previous
//
#include <hip/hip_runtime.h>
#include <math.h>

// Problem constants
#define BB 32
#define TT 512
#define INF_ 128
#define HH 256
#define H3 768
#define NHEADS 4
#define HDIM 64

typedef _Float16 half_t;
typedef half_t half2_t __attribute__((ext_vector_type(2)));
typedef half_t half4_t __attribute__((ext_vector_type(4)));
typedef half_t f16x8 __attribute__((ext_vector_type(8)));
typedef float f32x4 __attribute__((ext_vector_type(4)));

#if defined(__has_builtin)
#if __has_builtin(__builtin_amdgcn_fdot2)
#define FDOT2(a, b, c) __builtin_amdgcn_fdot2((a), (b), (c), false)
#endif
#endif
#ifndef FDOT2
#define FDOT2(a, b, c) fmaf((float)(a).x, (float)(b).x, fmaf((float)(a).y, (float)(b).y, (c)))
#endif

#define BCH(x) __builtin_bit_cast(half2_t, x)
#define PKH(a, b) __builtin_bit_cast(unsigned, half2_t{(half_t)(a), (half_t)(b)})

// ---------------- wave helpers (wave = 64 on CDNA) ----------------
__device__ __forceinline__ float wsum(float v) {
#pragma unroll
  for (int o = 32; o > 0; o >>= 1) v += __shfl_xor(v, o, 64);
  return v;
}
__device__ __forceinline__ float wmax(float v) {
#pragma unroll
  for (int o = 32; o > 0; o >>= 1) v = fmaxf(v, __shfl_xor(v, o, 64));
  return v;
}

// ---------------- fp32 -> f16 cast (n % 1024 == 0) ----------------
__global__ void castk(const float* __restrict__ s, half_t* __restrict__ d, int n) {
  int i = (blockIdx.x * 256 + threadIdx.x) * 4;
  if (i < n) {
    float4 v = *(const float4*)(s + i);
    half4_t o = {(half_t)v.x, (half_t)v.y, (half_t)v.z, (half_t)v.w};
    *(half4_t*)(d + i) = o;
  }
}

__device__ __forceinline__ f16x8 pk16(float4 a, float4 b) {
  return f16x8{(half_t)a.x, (half_t)a.y, (half_t)a.z, (half_t)a.w,
               (half_t)b.x, (half_t)b.y, (half_t)b.z, (half_t)b.w};
}

// ---------------- MFMA f16 GEMM: C[M,N] = A[M,K] * B[N,K]^T + bias -------
__global__ __launch_bounds__(256) void gemm_f16(
    const half_t* __restrict__ A, const half_t* __restrict__ B,
    const float* __restrict__ bias, float* __restrict__ C,
    int M, int N, int K) {
  __shared__ __align__(16) half_t As[128][40];
  __shared__ __align__(16) half_t Bs[64][40];
  const int tid = threadIdx.x;
  const int wave = tid >> 6, lane = tid & 63;
  const int m0 = blockIdx.y * 128, n0 = blockIdx.x * 64;
  const int mrow = lane & 15, quad = lane >> 4;
  f32x4 acc00 = {0.f, 0.f, 0.f, 0.f}, acc01 = acc00, acc02 = acc00, acc03 = acc00;
  f32x4 acc10 = acc00, acc11 = acc00, acc12 = acc00, acc13 = acc00;
  for (int k0 = 0; k0 < K; k0 += 32) {
    __syncthreads();  // previous iter's fragments consumed
#pragma unroll
    for (int u = 0; u < 2; ++u) {  // stage A: 128 rows x 32 halfs
      int idx = tid + u * 256;
      int row = idx >> 2, seg = idx & 3;
      *(f16x8*)&As[row][seg * 8] =
          *(const f16x8*)&A[(size_t)(m0 + row) * K + k0 + seg * 8];
    }
    {  // stage B: 64 rows x 32 halfs
      int row = tid >> 2, seg = tid & 3;
      *(f16x8*)&Bs[row][seg * 8] =
          *(const f16x8*)&B[(size_t)(n0 + row) * K + k0 + seg * 8];
    }
    __syncthreads();
    f16x8 af0 = *(const f16x8*)&As[wave * 32 + mrow][quad * 8];
    f16x8 af1 = *(const f16x8*)&As[wave * 32 + 16 + mrow][quad * 8];
    f16x8 bf0 = *(const f16x8*)&Bs[mrow][quad * 8];
    f16x8 bf1 = *(const f16x8*)&Bs[16 + mrow][quad * 8];
    f16x8 bf2 = *(const f16x8*)&Bs[32 + mrow][quad * 8];
    f16x8 bf3 = *(const f16x8*)&Bs[48 + mrow][quad * 8];
    acc00 = __builtin_amdgcn_mfma_f32_16x16x32_f16(af0, bf0, acc00, 0, 0, 0);
    acc01 = __builtin_amdgcn_mfma_f32_16x16x32_f16(af0, bf1, acc01, 0, 0, 0);
    acc02 = __builtin_amdgcn_mfma_f32_16x16x32_f16(af0, bf2, acc02, 0, 0, 0);
    acc03 = __builtin_amdgcn_mfma_f32_16x16x32_f16(af0, bf3, acc03, 0, 0, 0);
    acc10 = __builtin_amdgcn_mfma_f32_16x16x32_f16(af1, bf0, acc10, 0, 0, 0);
    acc11 = __builtin_amdgcn_mfma_f32_16x16x32_f16(af1, bf1, acc11, 0, 0, 0);
    acc12 = __builtin_amdgcn_mfma_f32_16x16x32_f16(af1, bf2, acc12, 0, 0, 0);
    acc13 = __builtin_amdgcn_mfma_f32_16x16x32_f16(af1, bf3, acc13, 0, 0, 0);
  }
  float bv0 = bias ? bias[n0 + mrow] : 0.f;
  float bv1 = bias ? bias[n0 + 16 + mrow] : 0.f;
  float bv2 = bias ? bias[n0 + 32 + mrow] : 0.f;
  float bv3 = bias ? bias[n0 + 48 + mrow] : 0.f;
  const int rb = m0 + wave * 32 + quad * 4;
#pragma unroll
  for (int r = 0; r < 4; ++r) {
    float* c0 = C + (size_t)(rb + r) * N + n0;
    c0[mrow] = acc00[r] + bv0;
    c0[16 + mrow] = acc01[r] + bv1;
    c0[32 + mrow] = acc02[r] + bv2;
    c0[48 + mrow] = acc03[r] + bv3;
    float* c1 = C + (size_t)(rb + 16 + r) * N + n0;
    c1[mrow] = acc10[r] + bv0;
    c1[16 + mrow] = acc11[r] + bv1;
    c1[32 + mrow] = acc12[r] + bv2;
    c1[48 + mrow] = acc13[r] + bv3;
  }
}

// ---------------- GRU recurrence: all-register weights, zero LDS stream ---
// R5 analysis: R14 (693 us) is LDS-STREAM-bound, not VALU-bound: 19
// ds_read_b128/thread/step = ~1700 cyc/SIMD of LDS pipe vs 768 cyc FDOT2.
// The 76 half2 streamed weights existed only because __launch_bounds__(512)
// let the compiler cap VGPR at 128. Fix: __launch_bounds__(512,2) -> 256
// budget (same occupancy: 8 waves/block, 2/SIMD, 1 block/CU). All 192 half2
// weights (3 gates x 64) now register-resident as scalar half2 (1-reg units
// -- allocator-friendly, unlike R1-R4's 4-aligned f16x8 tuples). Per step:
// 192 FDOT2 + 16 broadcast h-reads (free) + gate math + 1 barrier.
#define LDW(g, p, a, b, i)                             \
  {                                                    \
    float4 v = (p)[i];                                 \
    g##a = half2_t{(half_t)v.x, (half_t)v.y};          \
    g##b = half2_t{(half_t)v.z, (half_t)v.w};          \
  }
#define LDW32(g, p)                                                        \
  LDW(g, p, 0, 1, 0) LDW(g, p, 2, 3, 1) LDW(g, p, 4, 5, 2)                 \
  LDW(g, p, 6, 7, 3) LDW(g, p, 8, 9, 4) LDW(g, p, 10, 11, 5)               \
  LDW(g, p, 12, 13, 6) LDW(g, p, 14, 15, 7) LDW(g, p, 16, 17, 8)           \
  LDW(g, p, 18, 19, 9) LDW(g, p, 20, 21, 10) LDW(g, p, 22, 23, 11)         \
  LDW(g, p, 24, 25, 12) LDW(g, p, 26, 27, 13) LDW(g, p, 28, 29, 14)        \
  LDW(g, p, 30, 31, 15) LDW(g, p, 32, 33, 16) LDW(g, p, 34, 35, 17)        \
  LDW(g, p, 36, 37, 18) LDW(g, p, 38, 39, 19) LDW(g, p, 40, 41, 20)        \
  LDW(g, p, 42, 43, 21) LDW(g, p, 44, 45, 22) LDW(g, p, 46, 47, 23)        \
  LDW(g, p, 48, 49, 24) LDW(g, p, 50, 51, 25) LDW(g, p, 52, 53, 26)        \
  LDW(g, p, 54, 55, 27) LDW(g, p, 56, 57, 28) LDW(g, p, 58, 59, 29)        \
  LDW(g, p, 60, 61, 30) LDW(g, p, 62, 63, 31)

#define DECL64(g)                                                          \
  half2_t g##0, g##1, g##2, g##3, g##4, g##5, g##6, g##7, g##8, g##9,      \
      g##10, g##11, g##12, g##13, g##14, g##15, g##16, g##17, g##18,       \
      g##19, g##20, g##21, g##22, g##23, g##24, g##25, g##26, g##27,       \
      g##28, g##29, g##30, g##31, g##32, g##33, g##34, g##35, g##36,       \
      g##37, g##38, g##39, g##40, g##41, g##42, g##43, g##44, g##45,       \
      g##46, g##47, g##48, g##49, g##50, g##51, g##52, g##53, g##54,       \
      g##55, g##56, g##57, g##58, g##59, g##60, g##61, g##62, g##63;

// one 8-dim chunk: r,z,n all from registers
#define CHR(c8, a0, a1, a2, a3)                                            \
  {                                                                        \
    float4 v = hp4[c8];                                                    \
    half2_t t0 = __builtin_bit_cast(half2_t, v.x);                         \
    half2_t t1 = __builtin_bit_cast(half2_t, v.y);                         \
    half2_t t2 = __builtin_bit_cast(half2_t, v.z);                         \
    half2_t t3 = __builtin_bit_cast(half2_t, v.w);                         \
    ar = FDOT2(wr##a0, t0, ar); az = FDOT2(wz##a0, t0, az); an = FDOT2(wn##a0, t0, an); \
    ar = FDOT2(wr##a1, t1, ar); az = FDOT2(wz##a1, t1, az); an = FDOT2(wn##a1, t1, an); \
    ar = FDOT2(wr##a2, t2, ar); az = FDOT2(wz##a2, t2, az); an = FDOT2(wn##a2, t2, an); \
    ar = FDOT2(wr##a3, t3, ar); az = FDOT2(wz##a3, t3, az); an = FDOT2(wn##a3, t3, an); \
  }

__global__ __launch_bounds__(512, 2) void gru_layer(
    const float* __restrict__ xp, const float* __restrict__ Whh,
    const float* __restrict__ bhh, float* __restrict__ out,
    half_t* __restrict__ out16) {
  __shared__ __align__(16) half_t hs[2][2][144];
  const int tid = threadIdx.x;
  const int kh = tid & 1, j = tid >> 1;
  const int b = blockIdx.x;
  const bool wf32 = (out != nullptr);  // uniform: layer 0 skips fp32 h-store
  DECL64(wr)
  DECL64(wz)
  DECL64(wn)
  {
    const float4* pr = (const float4*)(Whh + (size_t)j * HH + kh * 128);
    const float4* pz = (const float4*)(Whh + (size_t)(HH + j) * HH + kh * 128);
    const float4* pn = (const float4*)(Whh + (size_t)(2 * HH + j) * HH + kh * 128);
    LDW32(wr, pr)
    LDW32(wz, pz)
    LDW32(wn, pn)
  }
  const float br = bhh[j], bz = bhh[HH + j], bn = bhh[2 * HH + j];
  for (int i = tid; i < 288; i += 512) ((unsigned*)hs)[i] = 0u;
  __syncthreads();
  float hprev = 0.f;
  const float* xrow = xp + (size_t)b * TT * H3;
  float* orow = out + (size_t)b * TT * HH;
  half_t* orow16 = out16 + (size_t)b * TT * HH;
  for (int t = 0; t < TT; ++t) {
    float xr = xrow[j], xz = xrow[HH + j], xn = xrow[2 * HH + j];
    const float4* hp4 = (const float4*)&hs[t & 1][kh][0];
    float ar = 0.f, az = 0.f, an = 0.f;
    CHR(0, 0, 1, 2, 3)
    CHR(1, 4, 5, 6, 7)
    CHR(2, 8, 9, 10, 11)
    CHR(3, 12, 13, 14, 15)
    CHR(4, 16, 17, 18, 19)
    CHR(5, 20, 21, 22, 23)
    CHR(6, 24, 25, 26, 27)
    CHR(7, 28, 29, 30, 31)
    CHR(8, 32, 33, 34, 35)
    CHR(9, 36, 37, 38, 39)
    CHR(10, 40, 41, 42, 43)
    CHR(11, 44, 45, 46, 47)
    CHR(12, 48, 49, 50, 51)
    CHR(13, 52, 53, 54, 55)
    CHR(14, 56, 57, 58, 59)
    CHR(15, 60, 61, 62, 63)
    ar += __shfl_xor(ar, 1);
    az += __shfl_xor(az, 1);
    an += __shfl_xor(an, 1);
    float rg = 1.f / (1.f + __expf(-(xr + ar + br)));
    float zg = 1.f / (1.f + __expf(-(xz + az + bz)));
    float ng = 2.f / (1.f + __expf(-2.f * (xn + rg * (an + bn)))) - 1.f;  // tanh, inf-safe
    float hnew = (1.f - zg) * ng + zg * hprev;
    hprev = hnew;
    float hpart = __shfl_xor(hnew, 2);  // lane (kh=0, even j) gets h_{j+1}
    if ((tid & 3) == 0) {               // kh==0 && j even: one b32 packed write
      half2_t pk;
      pk.x = (half_t)hnew;
      pk.y = (half_t)hpart;
      *(half2_t*)&hs[(t + 1) & 1][j >> 7][j & 127] = pk;
    }
    if (kh == 0) {
      orow16[j] = (half_t)hnew;
      if (wf32) orow[j] = hnew;
    }
    __syncthreads();
    xrow += H3;
    orow += HH;
    orow16 += HH;
  }
}

// ---------------- gat_W transpose -> f16: [4,256,64] -> [256 cols][256 k] --
__global__ void gat_wt(const float* __restrict__ W, half_t* __restrict__ Wt) {
  int idx = blockIdx.x * 256 + threadIdx.x;  // [0, 65536)
  int col = idx >> 8, k = idx & 255;
  Wt[idx] = (half_t)W[((size_t)((col >> 6) * HH + k)) * HDIM + (col & 63)];
}

// ---------------- GAT f_src/f_dst ----------------
__global__ void gat_fsd(const float* __restrict__ hgat, const float* __restrict__ a,
                        float* __restrict__ fsrc, float* __restrict__ fdst) {
  int b = blockIdx.x, hd = blockIdx.y, t = threadIdx.x;  // block 512
  const float* hp = hgat + ((size_t)(b * TT + t)) * HH + hd * HDIM;
  const float* ap = a + hd * 2 * HDIM;
  float fs = 0.f, fd = 0.f;
#pragma unroll 4
  for (int d = 0; d < HDIM; ++d) {
    float hv = hp[d];
    fs += hv * ap[d];
    fd += hv * ap[HDIM + d];
  }
  fsrc[(b * NHEADS + hd) * TT + t] = fs;
  fdst[(b * NHEADS + hd) * TT + t] = fd;
}

// ---------------- GAT flash attention (MFMA PV) ---------------------------
// Block = 64 q rows (grid 8 x 4 hd x 32 b), 4 waves x 16 q. Scores are
// rank-1 (fi + fd[j]) -> softmax on VALU, lane owns q=lane&15, j-range
// quad*32..+32. P stored f16 in LDS [q][j]; PV = P[16,128] @ H^T[64,128]^T
// on the matrix pipe using the gemm_f16 fragment conventions (A-frag
// [m=lane&15][k=(lane>>4)*8+i], C row=(lane>>4)*4+r col=lane&15).
__global__ __launch_bounds__(256) void gat_attn(
    const float* __restrict__ hgat, const float* __restrict__ fsrc,
    const float* __restrict__ fdst, float* __restrict__ out) {
  __shared__ __align__(16) half_t Htt[64][136];     // H^T per j-tile
  __shared__ __align__(16) half_t Ps[4][16][136];   // per-wave P (f16)
  __shared__ __align__(16) float fd[128];
  const int tid = threadIdx.x, wave = tid >> 6, lane = tid & 63;
  const int mrow = lane & 15, quad = lane >> 4;
  const int hd = blockIdx.y, b = blockIdx.z;
  const int q0 = blockIdx.x * 64;
  const float fi = fsrc[(size_t)(b * NHEADS + hd) * TT + q0 + wave * 16 + mrow];
  const float* fdp = fdst + (size_t)(b * NHEADS + hd) * TT;
  float m = -1e30f, l = 0.f;
  f32x4 o[4];
#pragma unroll
  for (int n = 0; n < 4; ++n) o[n] = f32x4{0.f, 0.f, 0.f, 0.f};
  for (int jt = 0; jt < TT; jt += 128) {
#pragma unroll
    for (int u = 0; u < 4; ++u) {  // stage H^T: Htt[d][j] (f16)
      int idx = tid + u * 256;
      int j = idx >> 3, s = (idx & 7) * 8;
      const float* hp = hgat + (size_t)(b * TT + jt + j) * HH + hd * HDIM + s;
      float4 ha = *(const float4*)hp, hb = *(const float4*)(hp + 4);
      Htt[s + 0][j] = (half_t)ha.x; Htt[s + 1][j] = (half_t)ha.y;
      Htt[s + 2][j] = (half_t)ha.z; Htt[s + 3][j] = (half_t)ha.w;
      Htt[s + 4][j] = (half_t)hb.x; Htt[s + 5][j] = (half_t)hb.y;
      Htt[s + 6][j] = (half_t)hb.z; Htt[s + 7][j] = (half_t)hb.w;
    }
    if (tid < 32) *(float4*)&fd[tid * 4] = *(const float4*)&fdp[jt + tid * 4];
    __syncthreads();
    float p[32];
    float mx = -1e30f;
#pragma unroll
    for (int g = 0; g < 8; ++g) {
      float4 f4 = *(const float4*)&fd[quad * 32 + g * 4];
      float e0 = fi + f4.x; e0 = (e0 > 0.f) ? e0 : 0.2f * e0;
      float e1 = fi + f4.y; e1 = (e1 > 0.f) ? e1 : 0.2f * e1;
      float e2 = fi + f4.z; e2 = (e2 > 0.f) ? e2 : 0.2f * e2;
      float e3 = fi + f4.w; e3 = (e3 > 0.f) ? e3 : 0.2f * e3;
      p[g * 4 + 0] = e0; p[g * 4 + 1] = e1; p[g * 4 + 2] = e2; p[g * 4 + 3] = e3;
      mx = fmaxf(mx, fmaxf(fmaxf(e0, e1), fmaxf(e2, e3)));
    }
    mx = fmaxf(mx, __shfl_xor(mx, 16, 64));  // reduce over the 4 j-groups
    mx = fmaxf(mx, __shfl_xor(mx, 32, 64));
    float mn = fmaxf(m, mx);
    float corr = __expf(m - mn);
    m = mn;
    float ls = 0.f;
#pragma unroll
    for (int i = 0; i < 32; ++i) { p[i] = __expf(p[i] - mn); ls += p[i]; }
    ls += __shfl_xor(ls, 16, 64);
    ls += __shfl_xor(ls, 32, 64);
    l = l * corr + ls;
    float cr[4];  // corr for PV acc rows q' = quad*4+r (held by lane q')
#pragma unroll
    for (int r = 0; r < 4; ++r) cr[r] = __shfl(corr, quad * 4 + r, 64);
#pragma unroll
    for (int n = 0; n < 4; ++n) {
      o[n][0] *= cr[0]; o[n][1] *= cr[1]; o[n][2] *= cr[2]; o[n][3] *= cr[3];
    }
#pragma unroll
    for (int s8 = 0; s8 < 4; ++s8) {  // P f16 -> LDS [q][j]
      f16x8 pkv = {(half_t)p[s8 * 8 + 0], (half_t)p[s8 * 8 + 1],
                   (half_t)p[s8 * 8 + 2], (half_t)p[s8 * 8 + 3],
                   (half_t)p[s8 * 8 + 4], (half_t)p[s8 * 8 + 5],
                   (half_t)p[s8 * 8 + 6], (half_t)p[s8 * 8 + 7]};
      *(f16x8*)&Ps[wave][mrow][quad * 32 + s8 * 8] = pkv;
    }
    __syncthreads();
    f16x8 pa0 = *(const f16x8*)&Ps[wave][mrow][0 * 32 + quad * 8];
    f16x8 pa1 = *(const f16x8*)&Ps[wave][mrow][1 * 32 + quad * 8];
    f16x8 pa2 = *(const f16x8*)&Ps[wave][mrow][2 * 32 + quad * 8];
    f16x8 pa3 = *(const f16x8*)&Ps[wave][mrow][3 * 32 + quad * 8];
#pragma unroll
    for (int n = 0; n < 4; ++n) {
      f16x8 vb0 = *(const f16x8*)&Htt[n * 16 + mrow][0 * 32 + quad * 8];
      f16x8 vb1 = *(const f16x8*)&Htt[n * 16 + mrow][1 * 32 + quad * 8];
      f16x8 vb2 = *(const f16x8*)&Htt[n * 16 + mrow][2 * 32 + quad * 8];
      f16x8 vb3 = *(const f16x8*)&Htt[n * 16 + mrow][3 * 32 + quad * 8];
      o[n] = __builtin_amdgcn_mfma_f32_16x16x32_f16(pa0, vb0, o[n], 0, 0, 0);
      o[n] = __builtin_amdgcn_mfma_f32_16x16x32_f16(pa1, vb1, o[n], 0, 0, 0);
      o[n] = __builtin_amdgcn_mfma_f32_16x16x32_f16(pa2, vb2, o[n], 0, 0, 0);
      o[n] = __builtin_amdgcn_mfma_f32_16x16x32_f16(pa3, vb3, o[n], 0, 0, 0);
    }
    __syncthreads();  // before next tile's staging overwrites Htt
  }
  float lr[4];
#pragma unroll
  for (int r = 0; r < 4; ++r) lr[r] = __shfl(l, quad * 4 + r, 64);
#pragma unroll
  for (int n = 0; n < 4; ++n)
#pragma unroll
    for (int r = 0; r < 4; ++r)
      out[(size_t)(b * TT + q0 + wave * 16 + quad * 4 + r) * HH + hd * HDIM +
          n * 16 + mrow] = o[n][r] / lr[r];
}

// ---------------- residual + LayerNorm (f16 output for MFMA GEMM) ---------
__global__ __launch_bounds__(256) void ln_res(
    const float* __restrict__ g, const float* __restrict__ gat,
    const float* __restrict__ gamma, const float* __restrict__ beta,
    half_t* __restrict__ y16) {
  int wave = threadIdx.x >> 6, lane = threadIdx.x & 63;
  size_t n = (size_t)blockIdx.x * 4 + wave;
  float4 v = ((const float4*)(g + n * HH))[lane];
  float4 w = ((const float4*)(gat + n * HH))[lane];
  v.x += w.x; v.y += w.y; v.z += w.z; v.w += w.w;
  float mu = wsum(v.x + v.y + v.z + v.w) * (1.f / 256.f);
  float dx = v.x - mu, dy = v.y - mu, dz = v.z - mu, dw = v.w - mu;
  float var = wsum(dx * dx + dy * dy + dz * dz + dw * dw) * (1.f / 256.f);
  float rstd = rsqrtf(var + 1e-5f);
  float4 gm = ((const float4*)gamma)[lane];
  float4 bt = ((const float4*)beta)[lane];
  half4_t o = {(half_t)(dx * rstd * gm.x + bt.x), (half_t)(dy * rstd * gm.y + bt.y),
               (half_t)(dz * rstd * gm.z + bt.z), (half_t)(dw * rstd * gm.w + bt.w)};
  ((half4_t*)(y16 + n * HH))[lane] = o;
}

// ---------------- MHA flash attention (MFMA QK + PV, f16 ctx output) ------
// Block = 64 q (grid 8 x 4 hd x 32 b), 4 waves x 16 q. QK^T and PV on the
// matrix pipe; online softmax on S in C-layout (row q=(lane>>4)*4+r, col
// j=n*16+(lane&15)), j-reduce = per-lane over 8 accs + shfl_xor 1,2,4,8.
__global__ __launch_bounds__(256) void mha_attn(const float* __restrict__ qkv,
                                                half_t* __restrict__ ctx16) {
  __shared__ __align__(16) half_t Qs[64][72];
  __shared__ __align__(16) half_t Ks[128][72];
  __shared__ __align__(16) half_t Vt[64][136];
  __shared__ __align__(16) half_t Ps[4][16][136];
  const int tid = threadIdx.x, wave = tid >> 6, lane = tid & 63;
  const int mrow = lane & 15, quad = lane >> 4;
  const int hd = blockIdx.y, b = blockIdx.z;
  const int q0 = blockIdx.x * 64;
  {  // stage Q: 64 q x 64 d -> f16
    int r = tid >> 2, s = (tid & 3) * 16;
    const float* src = qkv + (size_t)(b * TT + q0 + r) * H3 + hd * HDIM + s;
    float4 a = *(const float4*)src, b4 = *(const float4*)(src + 4);
    float4 c = *(const float4*)(src + 8), d4 = *(const float4*)(src + 12);
    *(f16x8*)&Qs[r][s] = pk16(a, b4);
    *(f16x8*)&Qs[r][s + 8] = pk16(c, d4);
  }
  __syncthreads();
  f16x8 qa0 = *(const f16x8*)&Qs[wave * 16 + mrow][quad * 8];
  f16x8 qa1 = *(const f16x8*)&Qs[wave * 16 + mrow][32 + quad * 8];
  float m[4] = {-1e30f, -1e30f, -1e30f, -1e30f};
  float l[4] = {0.f, 0.f, 0.f, 0.f};
  f32x4 o[4];
#pragma unroll
  for (int n = 0; n < 4; ++n) o[n] = f32x4{0.f, 0.f, 0.f, 0.f};
  for (int jt = 0; jt < TT; jt += 128) {
#pragma unroll
    for (int u = 0; u < 4; ++u) {  // stage K [j][d] and V^T [d][j]
      int idx = tid + u * 256;
      int j = idx >> 3, s = (idx & 7) * 8;
      const float* kp = qkv + (size_t)(b * TT + jt + j) * H3 + HH + hd * HDIM + s;
      float4 ka = *(const float4*)kp, kb = *(const float4*)(kp + 4);
      *(f16x8*)&Ks[j][s] = pk16(ka, kb);
      const float* vp = kp + HH;
      float4 va = *(const float4*)vp, vb = *(const float4*)(vp + 4);
      Vt[s + 0][j] = (half_t)va.x; Vt[s + 1][j] = (half_t)va.y;
      Vt[s + 2][j] = (half_t)va.z; Vt[s + 3][j] = (half_t)va.w;
      Vt[s + 4][j] = (half_t)vb.x; Vt[s + 5][j] = (half_t)vb.y;
      Vt[s + 6][j] = (half_t)vb.z; Vt[s + 7][j] = (half_t)vb.w;
    }
    __syncthreads();
    f32x4 sAcc[8];
#pragma unroll
    for (int n = 0; n < 8; ++n) sAcc[n] = f32x4{0.f, 0.f, 0.f, 0.f};
#pragma unroll
    for (int n = 0; n < 8; ++n) {
      f16x8 kb0 = *(const f16x8*)&Ks[n * 16 + mrow][quad * 8];
      f16x8 kb1 = *(const f16x8*)&Ks[n * 16 + mrow][32 + quad * 8];
      sAcc[n] = __builtin_amdgcn_mfma_f32_16x16x32_f16(qa0, kb0, sAcc[n], 0, 0, 0);
      sAcc[n] = __builtin_amdgcn_mfma_f32_16x16x32_f16(qa1, kb1, sAcc[n], 0, 0, 0);
    }
    float p[8][4];
    float mx[4] = {-1e30f, -1e30f, -1e30f, -1e30f};
#pragma unroll
    for (int n = 0; n < 8; ++n)
#pragma unroll
      for (int r = 0; r < 4; ++r) {
        float v = sAcc[n][r] * 0.125f;
        p[n][r] = v;
        mx[r] = fmaxf(mx[r], v);
      }
#pragma unroll
    for (int off = 8; off > 0; off >>= 1)
#pragma unroll
      for (int r = 0; r < 4; ++r) mx[r] = fmaxf(mx[r], __shfl_xor(mx[r], off, 64));
    float corr[4], ls[4];
#pragma unroll
    for (int r = 0; r < 4; ++r) {
      float mn = fmaxf(m[r], mx[r]);
      corr[r] = __expf(m[r] - mn);
      m[r] = mn;
      ls[r] = 0.f;
    }
#pragma unroll
    for (int n = 0; n < 8; ++n)
#pragma unroll
      for (int r = 0; r < 4; ++r) {
        float e = __expf(p[n][r] - m[r]);
        p[n][r] = e;
        ls[r] += e;
      }
#pragma unroll
    for (int off = 8; off > 0; off >>= 1)
#pragma unroll
      for (int r = 0; r < 4; ++r) ls[r] += __shfl_xor(ls[r], off, 64);
#pragma unroll
    for (int r = 0; r < 4; ++r) l[r] = l[r] * corr[r] + ls[r];
#pragma unroll
    for (int n = 0; n < 4; ++n) {
      o[n][0] *= corr[0]; o[n][1] *= corr[1]; o[n][2] *= corr[2]; o[n][3] *= corr[3];
    }
#pragma unroll
    for (int n = 0; n < 8; ++n)
#pragma unroll
      for (int r = 0; r < 4; ++r)
        Ps[wave][quad * 4 + r][n * 16 + mrow] = (half_t)p[n][r];
    __syncthreads();
    f16x8 pa0 = *(const f16x8*)&Ps[wave][mrow][0 * 32 + quad * 8];
    f16x8 pa1 = *(const f16x8*)&Ps[wave][mrow][1 * 32 + quad * 8];
    f16x8 pa2 = *(const f16x8*)&Ps[wave][mrow][2 * 32 + quad * 8];
    f16x8 pa3 = *(const f16x8*)&Ps[wave][mrow][3 * 32 + quad * 8];
#pragma unroll
    for (int n = 0; n < 4; ++n) {
      f16x8 vb0 = *(const f16x8*)&Vt[n * 16 + mrow][0 * 32 + quad * 8];
      f16x8 vb1 = *(const f16x8*)&Vt[n * 16 + mrow][1 * 32 + quad * 8];
      f16x8 vb2 = *(const f16x8*)&Vt[n * 16 + mrow][2 * 32 + quad * 8];
      f16x8 vb3 = *(const f16x8*)&Vt[n * 16 + mrow][3 * 32 + quad * 8];
      o[n] = __builtin_amdgcn_mfma_f32_16x16x32_f16(pa0, vb0, o[n], 0, 0, 0);
      o[n] = __builtin_amdgcn_mfma_f32_16x16x32_f16(pa1, vb1, o[n], 0, 0, 0);
      o[n] = __builtin_amdgcn_mfma_f32_16x16x32_f16(pa2, vb2, o[n], 0, 0, 0);
      o[n] = __builtin_amdgcn_mfma_f32_16x16x32_f16(pa3, vb3, o[n], 0, 0, 0);
    }
    __syncthreads();  // before next tile's staging overwrites Ks/Vt
  }
#pragma unroll
  for (int n = 0; n < 4; ++n)
#pragma unroll
    for (int r = 0; r < 4; ++r)
      ctx16[(size_t)(b * TT + q0 + wave * 16 + quad * 4 + r) * HH + hd * HDIM +
            n * 16 + mrow] = (half_t)(o[n][r] / l[r]);
}

// ---------------- mean pool over T ----------------
__global__ void mean_pool(const float* __restrict__ x, float* __restrict__ out) {
  int b = blockIdx.x, j = threadIdx.x;
  const float* p = x + (size_t)b * TT * HH + j;
  float s = 0.f;
  for (int t = 0; t < TT; ++t) s += p[(size_t)t * HH];
  out[b * HH + j] = s * (1.f / 512.f);
}

// ---------------- FC layers ----------------
__global__ void fc1_k(const float* __restrict__ pooled, const float* __restrict__ w,
                      const float* __restrict__ bias, float* __restrict__ hid) {
  int b = blockIdx.x, o = threadIdx.x;  // 128 threads
  const float* pp = pooled + b * HH;
  const float* wp = w + o * HH;
  float s = 0.f;
#pragma unroll 4
  for (int k = 0; k < HH; ++k) s += pp[k] * wp[k];
  hid[b * 128 + o] = fmaxf(s + bias[o], 0.f);
}

__global__ void fc2_k(const float* __restrict__ hid, const float* __restrict__ w,
                      const float* __restrict__ bias, float* __restrict__ out) {
  int t = threadIdx.x;  // 256 = 32 m x 8 c
  int mm = t >> 3, c = t & 7;
  const float* hp = hid + mm * 128;
  const float* wp = w + c * 128;
  float s = 0.f;
#pragma unroll 4
  for (int k = 0; k < 128; ++k) s += hp[k] * wp[k];
  out[mm * 8 + c] = s + bias[c];
}

extern "C" void kernel_launch(void* const* d_in, const int* in_sizes, int n_in,
                              void* d_out, int out_size, void* d_ws, size_t ws_size,
                              hipStream_t stream) {
  (void)in_sizes; (void)n_in; (void)out_size; (void)ws_size;
  const float* x    = (const float*)d_in[0];
  const float* Wih0 = (const float*)d_in[1];
  const float* Whh0 = (const float*)d_in[2];
  const float* bih0 = (const float*)d_in[3];
  const float* bhh0 = (const float*)d_in[4];
  const float* Wih1 = (const float*)d_in[5];
  const float* Whh1 = (const float*)d_in[6];
  const float* bih1 = (const float*)d_in[7];
  const float* bhh1 = (const float*)d_in[8];
  const float* gatW = (const float*)d_in[9];
  const float* gatA = (const float*)d_in[10];
  const float* lng  = (const float*)d_in[11];
  const float* lnb  = (const float*)d_in[12];
  const float* inw  = (const float*)d_in[13];
  const float* inb  = (const float*)d_in[14];
  const float* outw = (const float*)d_in[15];
  const float* outb = (const float*)d_in[16];
  const float* f1w  = (const float*)d_in[17];
  const float* f1b  = (const float*)d_in[18];
  const float* f2w  = (const float*)d_in[19];
  const float* f2b  = (const float*)d_in[20];
  float* out = (float*)d_out;
  float* ws = (float*)d_ws;

  // fp32 regions:
  float* XPA   = ws;                  // 16384*768: xp0 -> xp1 -> qkv
  float* G0    = ws + 12582912;       // gat_out (gru0 fp32 h never stored)
  float* G1    = G0 + 4194304;        // gru1-out (fp32, for ln_res)
  float* Yb    = G1 + 4194304;        // [f16 G0_16 | f16 G1_16] -> attn_out fp32
  float* HGAT  = Yb + 4194304;        // gat feats fp32 -> [f16 CTX16 | f16 Y16]
  float* GATWTf= HGAT + 4194304;
  float* FSRC  = GATWTf + 65536;
  float* FDST  = FSRC + 65536;
  float* POOL  = FDST + 65536;
  float* HIDb  = POOL + 8192;
  float* W16b  = HIDb + 4096;         // f16 weight pool (~1.1 MB)

  // f16 aliases (lifetimes verified against launch order):
  half_t* X16     = (half_t*)G1;                   // dead before gru1 writes G1
  half_t* G0_16   = (half_t*)Yb;                   // dead before attn_out write
  half_t* G1_16   = (half_t*)(Yb + 2097152);
  half_t* CTX16   = (half_t*)HGAT;                 // written after gat phase done
  half_t* Y16     = (half_t*)(HGAT + 2097152);
  half_t* GATWT16 = (half_t*)GATWTf;
  half_t* W16ih0  = (half_t*)W16b;
  half_t* W16ih1  = (half_t*)(W16b + 49152);
  half_t* W16in   = (half_t*)(W16b + 49152 + 98304);
  half_t* W16out  = (half_t*)(W16b + 49152 + 98304 + 98304);

  // 0. casts (weights once; x once)
  castk<<<2048, 256, 0, stream>>>(x, X16, 2097152);
  castk<<<96, 256, 0, stream>>>(Wih0, W16ih0, 98304);
  castk<<<192, 256, 0, stream>>>(Wih1, W16ih1, 196608);
  castk<<<192, 256, 0, stream>>>(inw, W16in, 196608);
  castk<<<64, 256, 0, stream>>>(outw, W16out, 65536);
  gat_wt<<<256, 256, 0, stream>>>(gatW, GATWT16);
  // 1. xp0 = x @ W_ih0^T + b_ih0   (MFMA f16)
  gemm_f16<<<dim3(12, 128), 256, 0, stream>>>(X16, W16ih0, bih0, XPA, 16384, 768, 128);
  // 2. GRU layer 0 (fp32 h not needed -> nullptr)
  gru_layer<<<32, 512, 0, stream>>>(XPA, Whh0, bhh0, nullptr, G0_16);
  // 3. xp1 = g0 @ W_ih1^T + b_ih1
  gemm_f16<<<dim3(12, 128), 256, 0, stream>>>(G0_16, W16ih1, bih1, XPA, 16384, 768, 256);
  // 4. GRU layer 1
  gru_layer<<<32, 512, 0, stream>>>(XPA, Whh1, bhh1, G1, G1_16);
  // 5. GAT per-head features + attention
  gemm_f16<<<dim3(4, 128), 256, 0, stream>>>(G1_16, GATWT16, nullptr, HGAT, 16384, 256, 256);
  gat_fsd<<<dim3(32, 4), 512, 0, stream>>>(HGAT, gatA, FSRC, FDST);
  gat_attn<<<dim3(8, 4, 32), 256, 0, stream>>>(HGAT, FSRC, FDST, G0);
  // 6. y = LN(g + gat_out) -> f16
  ln_res<<<4096, 256, 0, stream>>>(G1, G0, lng, lnb, Y16);
  // 7. MHA
  gemm_f16<<<dim3(12, 128), 256, 0, stream>>>(Y16, W16in, inb, XPA, 16384, 768, 256);
  mha_attn<<<dim3(8, 4, 32), 256, 0, stream>>>(XPA, CTX16);
  gemm_f16<<<dim3(4, 128), 256, 0, stream>>>(CTX16, W16out, outb, Yb, 16384, 256, 256);
  // 8. pool + FC head
  mean_pool<<<32, 256, 0, stream>>>(Yb, POOL);
  fc1_k<<<32, 128, 0, stream>>>(POOL, f1w, f1b, HIDb);
  fc2_k<<<1, 256, 0, stream>>>(HIDb, f2w, f2b, out);
}